// Round 6
// baseline (3247.856 us; speedup 1.0000x reference)
//
#include <hip/hip_runtime.h>
#include <hip/hip_fp16.h>

#define NU 100000
#define NI 50000
#define NN 150000
#define DD 64
#define KK 32
#define EUI 1000000
#define EUU 500000
#define EII 500000

static inline int cdiv(long a, int b) { return (int)((a + b - 1) / b); }

// ---------------- CSR build ----------------

__global__ void k_count(const int* __restrict__ h, int* __restrict__ cnt, int E) {
    int e = blockIdx.x * blockDim.x + threadIdx.x;
    if (e < E) atomicAdd(&cnt[h[e]], 1);
}

__global__ __launch_bounds__(1024) void k_scan(const int* __restrict__ cnt,
                                               int* __restrict__ rp, int n) {
    __shared__ int wsum[16];
    __shared__ int carry_s;
    int tid = threadIdx.x;
    int lane = tid & 63, wid = tid >> 6;
    if (tid == 0) carry_s = 0;
    __syncthreads();
    for (int base = 0; base < n; base += 1024) {
        int i = base + tid;
        int v = (i < n) ? cnt[i] : 0;
        int s = v;
#pragma unroll
        for (int off = 1; off < 64; off <<= 1) {
            int t = __shfl_up(s, off, 64);
            if (lane >= off) s += t;
        }
        if (lane == 63) wsum[wid] = s;
        __syncthreads();
        int woff = 0, total = 0;
#pragma unroll
        for (int w = 0; w < 16; w++) { int ws = wsum[w]; total += ws; if (w < wid) woff += ws; }
        int carry = carry_s;
        if (i < n) rp[i] = carry + woff + (s - v);
        __syncthreads();
        if (tid == 0) carry_s = carry + total;
        __syncthreads();
    }
    if (tid == 0) rp[n] = carry_s;
}

__global__ void k_scatter(const int* __restrict__ h, const int* __restrict__ rp,
                          int* __restrict__ cur, int* __restrict__ lst, int E) {
    int e = blockIdx.x * blockDim.x + threadIdx.x;
    if (e >= E) return;
    int r = h[e];
    int p = rp[r] + atomicAdd(&cur[r], 1);
    lst[p] = e;
}

__global__ void k_dinv(const int* __restrict__ rpu, const int* __restrict__ rpi,
                       float* __restrict__ dinv) {
    int t = blockIdx.x * blockDim.x + threadIdx.x;
    if (t >= NN) return;
    int deg = (t < NU) ? rpu[t + 1] - rpu[t] : rpi[t - NU + 1] - rpi[t - NU];
    dinv[t] = deg > 0 ? rsqrtf((float)deg) : 0.0f;
}

__global__ void k_rowsum_inv(const int* __restrict__ rp, const int* __restrict__ lst,
                             const float* __restrict__ w, float* __restrict__ out, int n) {
    int r = blockIdx.x * blockDim.x + threadIdx.x;
    if (r >= n) return;
    float s = 0.f;
    int e1 = rp[r + 1];
    for (int e = rp[r]; e < e1; e++) s += w[lst[e]];
    out[r] = (s != 0.0f) ? 1.0f / s : 0.0f;
}

// Wd_g = W2[0:64] - W2[64:128]; Wd_t = W2[128:192] - W2[192:256]
__global__ void k_wdiff(const float* __restrict__ W2, float* __restrict__ Wd_g,
                        float* __restrict__ Wd_t) {
    int i = blockIdx.x * blockDim.x + threadIdx.x;
    if (i >= DD * DD) return;
    Wd_g[i] = W2[i] - W2[DD * DD + i];
    Wd_t[i] = W2[2 * DD * DD + i] - W2[3 * DD * DD + i];
}

// init: xh = fp16(concat(user,item)); acc = f32 same
__global__ void k_init(const float* __restrict__ ue, const float* __restrict__ ie,
                       __half* __restrict__ xh, float* __restrict__ acc) {
    size_t i = (size_t)blockIdx.x * blockDim.x + threadIdx.x;
    if (i >= (size_t)NN * DD) return;
    float v = (i < (size_t)NU * DD) ? ue[i] : ie[i - (size_t)NU * DD];
    xh[i] = __float2half(v);
    acc[i] = v;
}

// ---------------- pass A: per-edge contrib = alpha * dist, fp16, edge order ----------------

__global__ __launch_bounds__(256) void k_passA(
        const int* __restrict__ eh, const int* __restrict__ et, int toff,
        const __half* __restrict__ feat, const float* __restrict__ intents,
        __half* __restrict__ c_out, int E) {
    __shared__ float Wl[DD * KK];
    for (int idx = threadIdx.x; idx < DD * KK; idx += blockDim.x) Wl[idx] = intents[idx];
    __syncthreads();
    int e = blockIdx.x * blockDim.x + threadIdx.x;
    if (e >= E) return;
    const uint4* hp = (const uint4*)(feat + (size_t)eh[e] * DD);
    const uint4* tp = (const uint4*)(feat + (size_t)(et[e] + toff) * DD);
    uint4 hraw[8], traw[8];
#pragma unroll
    for (int j = 0; j < 8; j++) hraw[j] = hp[j];
#pragma unroll
    for (int j = 0; j < 8; j++) traw[j] = tp[j];
    const __half2* h2 = (const __half2*)hraw;
    const __half2* t2 = (const __half2*)traw;
    float logit[KK];
#pragma unroll
    for (int k = 0; k < KK; k++) logit[k] = 0.f;
    float dot = 0.f;
#pragma unroll 4
    for (int l4 = 0; l4 < 16; l4++) {
        float2 ha = __half22float2(h2[2 * l4]), hb = __half22float2(h2[2 * l4 + 1]);
        float2 ta = __half22float2(t2[2 * l4]), tb = __half22float2(t2[2 * l4 + 1]);
        float p0 = ha.x * ta.x, p1 = ha.y * ta.y, p2 = hb.x * tb.x, p3 = hb.y * tb.y;
        dot += p0 + p1 + p2 + p3;
        const float* w = &Wl[l4 * 4 * KK];
#pragma unroll
        for (int k = 0; k < KK; k++)
            logit[k] += p0 * w[k] + p1 * w[KK + k] + p2 * w[2 * KK + k] + p3 * w[3 * KK + k];
    }
    float m = logit[0];
#pragma unroll
    for (int k = 1; k < KK; k++) m = fmaxf(m, logit[k]);
    float ssum = 0.f;
#pragma unroll
    for (int k = 0; k < KK; k++) { float ev = __expf(logit[k] - m); logit[k] = ev; ssum += ev; }
    float scale = 0.5f * (dot + 1.0f) / ssum;   // alpha / softmax denom
    uint4 pk[4];
    unsigned int* u = (unsigned int*)pk;
#pragma unroll
    for (int k2 = 0; k2 < 16; k2++) {
        __half2 hh = __floats2half2_rn(logit[2 * k2] * scale, logit[2 * k2 + 1] * scale);
        u[k2] = *reinterpret_cast<const unsigned int*>(&hh);
    }
    uint4* dst = (uint4*)(c_out + (size_t)e * KK);
#pragma unroll
    for (int q = 0; q < 4; q++) dst[q] = pk[q];
}

// ---------------- pass B+C fused: agg -> recip -> edge weights (CSR order) + inv rowsum ----
__global__ __launch_bounds__(256) void k_passBC(const int* __restrict__ rp,
                                                const int* __restrict__ lst,
                                                const __half* __restrict__ c,
                                                float* __restrict__ w,
                                                float* __restrict__ rsinv, int n) {
    int gid = blockIdx.x * blockDim.x + threadIdx.x;
    int node = gid >> 3, j = gid & 7;
    if (node >= n) return;
    int p0 = rp[node], p1 = rp[node + 1];
    const uint2* cp = (const uint2*)c;   // 8 uint2 per 32-half row
    float4 agg = make_float4(0.f, 0.f, 0.f, 0.f);
    for (int p = p0; p < p1; p++) {
        uint2 v = cp[(size_t)lst[p] * 8 + j];
        float2 fa = __half22float2(*reinterpret_cast<const __half2*>(&v.x));
        float2 fb = __half22float2(*reinterpret_cast<const __half2*>(&v.y));
        agg.x += fa.x; agg.y += fa.y; agg.z += fb.x; agg.w += fb.y;
    }
    float4 rec;
    rec.x = (agg.x != 0.f) ? 1.f / agg.x : 0.f;
    rec.y = (agg.y != 0.f) ? 1.f / agg.y : 0.f;
    rec.z = (agg.z != 0.f) ? 1.f / agg.z : 0.f;
    rec.w = (agg.w != 0.f) ? 1.f / agg.w : 0.f;
    float rs = 0.f;
    for (int p = p0; p < p1; p++) {
        uint2 v = cp[(size_t)lst[p] * 8 + j];
        float2 fa = __half22float2(*reinterpret_cast<const __half2*>(&v.x));
        float2 fb = __half22float2(*reinterpret_cast<const __half2*>(&v.y));
        float dot = fa.x * rec.x + fa.y * rec.y + fb.x * rec.z + fb.y * rec.w;
        dot += __shfl_xor(dot, 1, 64);
        dot += __shfl_xor(dot, 2, 64);
        dot += __shfl_xor(dot, 4, 64);
        float wv = dot * (1.0f / KK);
        if (j == 0) w[p] = wv;
        rs += wv;
    }
    if (j == 0) rsinv[node] = (rs != 0.f) ? 1.f / rs : 0.f;
}

// ---------------- fused UI: g1 + t1 + z-preact, wave per row ----------------
__global__ __launch_bounds__(512) void k_fused_ui(
        const int* __restrict__ rp, const int* __restrict__ lst,
        const int* __restrict__ tails, int tail_off, int row_off,
        const float* __restrict__ w, const float* __restrict__ rsinv,
        const float* __restrict__ dinv, const float* __restrict__ Wd_g,
        const float* __restrict__ Wd_t, const float* __restrict__ b2,
        const __half* __restrict__ x, float* __restrict__ gs, float* __restrict__ ts,
        float* __restrict__ zp, int nrows) {
    __shared__ float Wg[DD * DD];
    __shared__ float Wt[DD * DD];
    for (int i = threadIdx.x; i < DD * DD; i += 512) { Wg[i] = Wd_g[i]; Wt[i] = Wd_t[i]; }
    __syncthreads();
    int r = blockIdx.x * 8 + (threadIdx.x >> 6);
    int lane = threadIdx.x & 63;
    if (r >= nrows) return;
    int row_g = r + row_off;
    float accg = 0.f, acct = 0.f;
    float dh = dinv[row_g];
    int e1 = rp[r + 1];
    for (int e = rp[r]; e < e1; e++) {
        int eid = lst[e];
        int col = tails[eid] + tail_off;
        float xv = __half2float(x[(size_t)col * DD + lane]);
        accg += dh * dinv[col] * xv;
        acct += w[e] * xv;
    }
    acct *= rsinv[r];
    float ss = acct * acct;
#pragma unroll
    for (int off = 32; off > 0; off >>= 1) ss += __shfl_xor(ss, off, 64);
    acct *= 1.0f / fmaxf(sqrtf(ss), 1e-12f);
    float zv = b2[lane];
#pragma unroll 8
    for (int l = 0; l < DD; l++) {
        float gl = __shfl(accg, l, 64);
        float tl = __shfl(acct, l, 64);
        zv += gl * Wg[l * DD + lane] + tl * Wt[l * DD + lane];
    }
    size_t oi = (size_t)row_g * DD + lane;
    gs[oi] = accg;
    ts[oi] = acct;
    zp[oi] = zv;
}

// ---------------- fused finalize (UU / II): g2 + t2 + gate + combine ----------------
__global__ __launch_bounds__(512) void k_fused_fin(
        const int* __restrict__ rp, const int* __restrict__ lst,
        const int* __restrict__ tails, int off,
        const float* __restrict__ base_w, const float* __restrict__ base_inv,
        const float* __restrict__ w, const float* __restrict__ rsinv,
        const float* __restrict__ W1, const float* __restrict__ W3,
        const __half* __restrict__ x, const float* __restrict__ gs,
        const float* __restrict__ ts, const float* __restrict__ zp,
        __half* __restrict__ xh_out, float* __restrict__ acc, int nrows) {
    __shared__ float Wa[DD * DD];
    __shared__ float Wb[DD * DD];
    for (int i = threadIdx.x; i < DD * DD; i += 512) { Wa[i] = W1[i]; Wb[i] = W3[i]; }
    __syncthreads();
    int r = blockIdx.x * 8 + (threadIdx.x >> 6);
    int lane = threadIdx.x & 63;
    if (r >= nrows) return;
    int row_g = r + off;
    float accg = 0.f, acct = 0.f;
    int e1 = rp[r + 1];
    for (int e = rp[r]; e < e1; e++) {
        int eid = lst[e];
        int col = tails[eid] + off;
        float xv = __half2float(x[(size_t)col * DD + lane]);
        accg += base_w[eid] * xv;
        acct += w[e] * xv;
    }
    accg *= base_inv[r];
    acct *= rsinv[r];
    float ss = acct * acct;
#pragma unroll
    for (int off2 = 32; off2 > 0; off2 >>= 1) ss += __shfl_xor(ss, off2, 64);
    acct *= 1.0f / fmaxf(sqrtf(ss), 1e-12f);
    size_t oi = (size_t)row_g * DD + lane;
    float gfin = gs[oi] + accg;
    float tfin = ts[oi] + acct;
    float zv = zp[oi];
#pragma unroll 8
    for (int l = 0; l < DD; l++) {
        float gl = __shfl(gfin, l, 64);
        float tl = __shfl(tfin, l, 64);
        zv += gl * Wa[l * DD + lane] + tl * Wb[l * DD + lane];
    }
    float gate = 1.0f / (1.0f + __expf(-zv));
    float xn = gate * gfin + (1.0f - gate) * tfin;
    xh_out[oi] = __float2half(xn);
    acc[oi] += xn;
}

// ---------------- host launcher ----------------

extern "C" void kernel_launch(void* const* d_in, const int* in_sizes, int n_in,
                              void* d_out, int out_size, void* d_ws, size_t ws_size,
                              hipStream_t stream) {
    const float* user_emb = (const float*)d_in[0];
    const float* item_emb = (const float*)d_in[1];
    const float* intents  = (const float*)d_in[2];
    const float* W2       = (const float*)d_in[3];
    const float* b2       = (const float*)d_in[4];
    const float* uu_w     = (const float*)d_in[5];
    const float* ii_w     = (const float*)d_in[6];
    const int*   ui_u     = (const int*)d_in[7];
    const int*   ui_i     = (const int*)d_in[8];
    const int*   uu_h     = (const int*)d_in[9];
    const int*   uu_t     = (const int*)d_in[10];
    const int*   ii_h     = (const int*)d_in[11];
    const int*   ii_t     = (const int*)d_in[12];
    float* acc = (float*)d_out;

    char* pw = (char*)d_ws;
    auto allocb = [&](size_t nbytes) -> char* {
        char* r = pw;
        pw += (nbytes + 255) & ~(size_t)255;
        return r;
    };
    // ~237 MB total (round-5's proven footprint)
    float* gs   = (float*)allocb((size_t)NN * DD * 4);
    float* ts   = (float*)allocb((size_t)NN * DD * 4);
    float* zp   = (float*)allocb((size_t)NN * DD * 4);
    __half* xh0 = (__half*)allocb((size_t)NN * DD * 2);
    __half* xh1 = (__half*)allocb((size_t)NN * DD * 2);
    __half* c   = (__half*)allocb((size_t)EUI * KK * 2);   // 64 MB, reused UI/UU/II
    float* w    = (float*)allocb((size_t)EUI * 4);
    float* rs   = (float*)allocb((size_t)NU * 4);
    float* dinv = (float*)allocb((size_t)NN * 4);
    float* iuu  = (float*)allocb((size_t)NU * 4);
    float* iii  = (float*)allocb((size_t)NI * 4);
    float* Wd_g = (float*)allocb((size_t)DD * DD * 4);
    float* Wd_t = (float*)allocb((size_t)DD * DD * 4);
    int* rp_u   = (int*)allocb(((size_t)NU + 1) * 4);
    int* rp_i   = (int*)allocb(((size_t)NI + 1) * 4);
    int* rp_uu  = (int*)allocb(((size_t)NU + 1) * 4);
    int* rp_ii  = (int*)allocb(((size_t)NI + 1) * 4);
    int* lst_u  = (int*)allocb((size_t)EUI * 4);
    int* lst_i  = (int*)allocb((size_t)EUI * 4);
    int* lst_uu = (int*)allocb((size_t)EUU * 4);
    int* lst_ii = (int*)allocb((size_t)EII * 4);
    int* cur    = (int*)c;   // alias: CSR build finishes before c is used

    const int B = 256;

    auto build_csr = [&](const int* h, int E, int n, int* rp, int* lst) {
        hipMemsetAsync(cur, 0, (size_t)n * 4, stream);
        k_count<<<cdiv(E, B), B, 0, stream>>>(h, cur, E);
        k_scan<<<1, 1024, 0, stream>>>(cur, rp, n);
        hipMemsetAsync(cur, 0, (size_t)n * 4, stream);
        k_scatter<<<cdiv(E, B), B, 0, stream>>>(h, rp, cur, lst, E);
    };

    build_csr(ui_u, EUI, NU, rp_u, lst_u);
    build_csr(ui_i, EUI, NI, rp_i, lst_i);
    build_csr(uu_h, EUU, NU, rp_uu, lst_uu);
    build_csr(ii_h, EII, NI, rp_ii, lst_ii);
    k_dinv<<<cdiv(NN, B), B, 0, stream>>>(rp_u, rp_i, dinv);
    k_rowsum_inv<<<cdiv(NU, B), B, 0, stream>>>(rp_uu, lst_uu, uu_w, iuu, NU);
    k_rowsum_inv<<<cdiv(NI, B), B, 0, stream>>>(rp_ii, lst_ii, ii_w, iii, NI);
    k_wdiff<<<cdiv(DD * DD, B), B, 0, stream>>>(W2, Wd_g, Wd_t);
    k_init<<<cdiv((long)NN * DD, B), B, 0, stream>>>(user_emb, item_emb, xh0, acc);

    for (int layer = 0; layer < 2; ++layer) {
        const __half* xin = (layer == 0) ? xh0 : xh1;
        __half* xout = (layer == 0) ? xh1 : xh0;

        // ---- UI: passA -> (passBC -> fused g1+t1+zpre) per side ----
        k_passA<<<cdiv(EUI, B), B, 0, stream>>>(ui_u, ui_i, NU, xin, intents, c, EUI);
        k_passBC<<<cdiv((long)NU * 8, B), B, 0, stream>>>(rp_u, lst_u, c, w, rs, NU);
        k_fused_ui<<<cdiv(NU, 8), 512, 0, stream>>>(rp_u, lst_u, ui_i, NU, 0, w, rs,
                                                    dinv, Wd_g, Wd_t, b2, xin, gs, ts, zp, NU);
        k_passBC<<<cdiv((long)NI * 8, B), B, 0, stream>>>(rp_i, lst_i, c, w, rs, NI);
        k_fused_ui<<<cdiv(NI, 8), 512, 0, stream>>>(rp_i, lst_i, ui_u, 0, NU, w, rs,
                                                    dinv, Wd_g, Wd_t, b2, xin, gs, ts, zp, NI);

        // ---- UU: passA -> passBC -> finalize user rows ----
        k_passA<<<cdiv(EUU, B), B, 0, stream>>>(uu_h, uu_t, 0, xin, intents, c, EUU);
        k_passBC<<<cdiv((long)NU * 8, B), B, 0, stream>>>(rp_uu, lst_uu, c, w, rs, NU);
        k_fused_fin<<<cdiv(NU, 8), 512, 0, stream>>>(rp_uu, lst_uu, uu_t, 0, uu_w, iuu,
                                                     w, rs, W2 + DD * DD, W2 + 3 * DD * DD,
                                                     xin, gs, ts, zp, xout, acc, NU);

        // ---- II: passA -> passBC -> finalize item rows ----
        k_passA<<<cdiv(EII, B), B, 0, stream>>>(ii_h, ii_t, 0, xin + (size_t)NU * DD, intents, c, EII);
        k_passBC<<<cdiv((long)NI * 8, B), B, 0, stream>>>(rp_ii, lst_ii, c, w, rs, NI);
        k_fused_fin<<<cdiv(NI, 8), 512, 0, stream>>>(rp_ii, lst_ii, ii_t, NU, ii_w, iii,
                                                     w, rs, W2 + DD * DD, W2 + 3 * DD * DD,
                                                     xin, gs, ts, zp, xout, acc, NI);
    }
}

// Round 7
// 2829.884 us; speedup vs baseline: 1.1477x; 1.1477x over previous
//
#include <hip/hip_runtime.h>
#include <hip/hip_fp16.h>

#define NU 100000
#define NI 50000
#define NN 150000
#define DD 64
#define KK 32
#define EUI 1000000
#define EUU 500000
#define EII 500000

static inline int cdiv(long a, int b) { return (int)((a + b - 1) / b); }

// ---------------- CSR build ----------------

__global__ void k_count(const int* __restrict__ h, int* __restrict__ cnt, int E) {
    int e = blockIdx.x * blockDim.x + threadIdx.x;
    if (e < E) atomicAdd(&cnt[h[e]], 1);
}

__global__ __launch_bounds__(1024) void k_scan(const int* __restrict__ cnt,
                                               int* __restrict__ rp, int n) {
    __shared__ int wsum[16];
    __shared__ int carry_s;
    int tid = threadIdx.x;
    int lane = tid & 63, wid = tid >> 6;
    if (tid == 0) carry_s = 0;
    __syncthreads();
    for (int base = 0; base < n; base += 1024) {
        int i = base + tid;
        int v = (i < n) ? cnt[i] : 0;
        int s = v;
#pragma unroll
        for (int off = 1; off < 64; off <<= 1) {
            int t = __shfl_up(s, off, 64);
            if (lane >= off) s += t;
        }
        if (lane == 63) wsum[wid] = s;
        __syncthreads();
        int woff = 0, total = 0;
#pragma unroll
        for (int w = 0; w < 16; w++) { int ws = wsum[w]; total += ws; if (w < wid) woff += ws; }
        int carry = carry_s;
        if (i < n) rp[i] = carry + woff + (s - v);
        __syncthreads();
        if (tid == 0) carry_s = carry + total;
        __syncthreads();
    }
    if (tid == 0) rp[n] = carry_s;
}

__global__ void k_scatter(const int* __restrict__ h, const int* __restrict__ rp,
                          int* __restrict__ cur, int* __restrict__ lst, int E) {
    int e = blockIdx.x * blockDim.x + threadIdx.x;
    if (e >= E) return;
    int r = h[e];
    int p = rp[r] + atomicAdd(&cur[r], 1);
    lst[p] = e;
}

__global__ void k_dinv(const int* __restrict__ rpu, const int* __restrict__ rpi,
                       float* __restrict__ dinv) {
    int t = blockIdx.x * blockDim.x + threadIdx.x;
    if (t >= NN) return;
    int deg = (t < NU) ? rpu[t + 1] - rpu[t] : rpi[t - NU + 1] - rpi[t - NU];
    dinv[t] = deg > 0 ? rsqrtf((float)deg) : 0.0f;
}

__global__ void k_rowsum_inv(const int* __restrict__ rp, const int* __restrict__ lst,
                             const float* __restrict__ w, float* __restrict__ out, int n) {
    int r = blockIdx.x * blockDim.x + threadIdx.x;
    if (r >= n) return;
    float s = 0.f;
    int e1 = rp[r + 1];
    for (int e = rp[r]; e < e1; e++) s += w[lst[e]];
    out[r] = (s != 0.0f) ? 1.0f / s : 0.0f;
}

__global__ void k_wdiff(const float* __restrict__ W2, float* __restrict__ Wd_g,
                        float* __restrict__ Wd_t) {
    int i = blockIdx.x * blockDim.x + threadIdx.x;
    if (i >= DD * DD) return;
    Wd_g[i] = W2[i] - W2[DD * DD + i];
    Wd_t[i] = W2[2 * DD * DD + i] - W2[3 * DD * DD + i];
}

__global__ void k_init(const float* __restrict__ ue, const float* __restrict__ ie,
                       __half* __restrict__ xh, float* __restrict__ acc) {
    size_t i = (size_t)blockIdx.x * blockDim.x + threadIdx.x;
    if (i >= (size_t)NN * DD) return;
    float v = (i < (size_t)NU * DD) ? ue[i] : ie[i - (size_t)NU * DD];
    xh[i] = __float2half(v);
    acc[i] = v;
}

// ---------------- map-building kernels (x-independent, run once) ----------------

__global__ void k_posU(const int* __restrict__ lst, int* __restrict__ pos, int E) {
    int p = blockIdx.x * blockDim.x + threadIdx.x;
    if (p < E) pos[lst[p]] = p;
}

__global__ void k_mapUI(const int* __restrict__ lst_i, const int* __restrict__ posU,
                        int* __restrict__ mUI, int E) {
    int p = blockIdx.x * blockDim.x + threadIdx.x;
    if (p < E) mUI[p] = posU[lst_i[p]];
}

__global__ void k_build_ui(const int* __restrict__ lst_u, const int* __restrict__ ui_u,
                           const int* __restrict__ ui_i, int* __restrict__ headU,
                           int* __restrict__ colU, int E) {
    int p = blockIdx.x * blockDim.x + threadIdx.x;
    if (p >= E) return;
    int e = lst_u[p];
    headU[p] = ui_u[e];
    colU[p] = ui_i[e] + NU;
}

__global__ void k_build_colI(const int* __restrict__ lst_i, const int* __restrict__ ui_u,
                             int* __restrict__ colI, int E) {
    int p = blockIdx.x * blockDim.x + threadIdx.x;
    if (p < E) colI[p] = ui_u[lst_i[p]];
}

// single-sided: head/col as GLOBAL node indices, bw = normalized base weight (CSR order)
__global__ void k_build_s(const int* __restrict__ lst, const int* __restrict__ eh,
                          const int* __restrict__ et, const float* __restrict__ ew,
                          const float* __restrict__ inv, int off,
                          int* __restrict__ head, int* __restrict__ col,
                          float* __restrict__ bw, int E) {
    int p = blockIdx.x * blockDim.x + threadIdx.x;
    if (p >= E) return;
    int e = lst[p];
    int h = eh[e];
    head[p] = h + off;
    col[p] = et[e] + off;
    bw[p] = ew[e] * inv[h];
}

// ---------------- pass A (CSR order): c[p] = alpha * dist, fp16 ----------------

__global__ __launch_bounds__(256) void k_passA(
        const int* __restrict__ head, const int* __restrict__ col,
        const __half* __restrict__ x, const float* __restrict__ intents,
        __half* __restrict__ c_out, int E) {
    __shared__ float Wl[DD * KK];
    for (int idx = threadIdx.x; idx < DD * KK; idx += blockDim.x) Wl[idx] = intents[idx];
    __syncthreads();
    int p = blockIdx.x * blockDim.x + threadIdx.x;
    if (p >= E) return;
    const uint4* hp = (const uint4*)(x + (size_t)head[p] * DD);
    const uint4* tp = (const uint4*)(x + (size_t)col[p] * DD);
    uint4 hraw[8], traw[8];
#pragma unroll
    for (int j = 0; j < 8; j++) hraw[j] = hp[j];
#pragma unroll
    for (int j = 0; j < 8; j++) traw[j] = tp[j];
    const __half2* h2 = (const __half2*)hraw;
    const __half2* t2 = (const __half2*)traw;
    float logit[KK];
#pragma unroll
    for (int k = 0; k < KK; k++) logit[k] = 0.f;
    float dot = 0.f;
#pragma unroll 4
    for (int l4 = 0; l4 < 16; l4++) {
        float2 ha = __half22float2(h2[2 * l4]), hb = __half22float2(h2[2 * l4 + 1]);
        float2 ta = __half22float2(t2[2 * l4]), tb = __half22float2(t2[2 * l4 + 1]);
        float p0 = ha.x * ta.x, p1 = ha.y * ta.y, p2 = hb.x * tb.x, p3 = hb.y * tb.y;
        dot += p0 + p1 + p2 + p3;
        const float* w = &Wl[l4 * 4 * KK];
#pragma unroll
        for (int k = 0; k < KK; k++)
            logit[k] += p0 * w[k] + p1 * w[KK + k] + p2 * w[2 * KK + k] + p3 * w[3 * KK + k];
    }
    float m = logit[0];
#pragma unroll
    for (int k = 1; k < KK; k++) m = fmaxf(m, logit[k]);
    float ssum = 0.f;
#pragma unroll
    for (int k = 0; k < KK; k++) { float ev = __expf(logit[k] - m); logit[k] = ev; ssum += ev; }
    float scale = 0.5f * (dot + 1.0f) / ssum;
    uint4 pk[4];
    unsigned int* u = (unsigned int*)pk;
#pragma unroll
    for (int k2 = 0; k2 < 16; k2++) {
        __half2 hh = __floats2half2_rn(logit[2 * k2] * scale, logit[2 * k2 + 1] * scale);
        u[k2] = *reinterpret_cast<const unsigned int*>(&hh);
    }
    uint4* dst = (uint4*)(c_out + (size_t)p * KK);
#pragma unroll
    for (int q = 0; q < 4; q++) dst[q] = pk[q];
}

// ---------------- pass B+C: agg -> recip -> edge weights + inv rowsum ----------------
// map==nullptr: c is in this CSR's order (stream). else: gather c rows via map[p].
__global__ __launch_bounds__(256) void k_passBC(const int* __restrict__ rp,
                                                const int* __restrict__ map,
                                                const __half* __restrict__ c,
                                                float* __restrict__ w,
                                                float* __restrict__ rsinv, int n) {
    int gid = blockIdx.x * blockDim.x + threadIdx.x;
    int node = gid >> 3, j = gid & 7;
    if (node >= n) return;
    int p0 = rp[node], p1 = rp[node + 1];
    const uint2* cp = (const uint2*)c;
    float4 agg = make_float4(0.f, 0.f, 0.f, 0.f);
    for (int p = p0; p < p1; p++) {
        int idx = map ? map[p] : p;
        uint2 v = cp[(size_t)idx * 8 + j];
        float2 fa = __half22float2(*reinterpret_cast<const __half2*>(&v.x));
        float2 fb = __half22float2(*reinterpret_cast<const __half2*>(&v.y));
        agg.x += fa.x; agg.y += fa.y; agg.z += fb.x; agg.w += fb.y;
    }
    float4 rec;
    rec.x = (agg.x != 0.f) ? 1.f / agg.x : 0.f;
    rec.y = (agg.y != 0.f) ? 1.f / agg.y : 0.f;
    rec.z = (agg.z != 0.f) ? 1.f / agg.z : 0.f;
    rec.w = (agg.w != 0.f) ? 1.f / agg.w : 0.f;
    float rs = 0.f;
    for (int p = p0; p < p1; p++) {
        int idx = map ? map[p] : p;
        uint2 v = cp[(size_t)idx * 8 + j];
        float2 fa = __half22float2(*reinterpret_cast<const __half2*>(&v.x));
        float2 fb = __half22float2(*reinterpret_cast<const __half2*>(&v.y));
        float dot = fa.x * rec.x + fa.y * rec.y + fb.x * rec.z + fb.y * rec.w;
        dot += __shfl_xor(dot, 1, 64);
        dot += __shfl_xor(dot, 2, 64);
        dot += __shfl_xor(dot, 4, 64);
        float wv = dot * (1.0f / KK);
        if (j == 0) w[p] = wv;
        rs += wv;
    }
    if (j == 0) rsinv[node] = (rs != 0.f) ? 1.f / rs : 0.f;
}

// ---------------- fused UI: g1 + t1 + z-preact, wave per row, 4x unrolled ----------------
__global__ __launch_bounds__(512) void k_fused_ui(
        const int* __restrict__ rp, const int* __restrict__ col,
        const float* __restrict__ w, const float* __restrict__ rsinv,
        const float* __restrict__ dinv, const float* __restrict__ Wd_g,
        const float* __restrict__ Wd_t, const float* __restrict__ b2,
        const __half* __restrict__ x, float* __restrict__ gs, float* __restrict__ ts,
        float* __restrict__ zp, int row_off, int nrows) {
    __shared__ float Wg[DD * DD];
    __shared__ float Wt[DD * DD];
    for (int i = threadIdx.x; i < DD * DD; i += 512) { Wg[i] = Wd_g[i]; Wt[i] = Wd_t[i]; }
    __syncthreads();
    int r = blockIdx.x * 8 + (threadIdx.x >> 6);
    int lane = threadIdx.x & 63;
    if (r >= nrows) return;
    int row_g = r + row_off;
    float accg = 0.f, acct = 0.f;
    int e = rp[r], e1 = rp[r + 1];
    for (; e + 4 <= e1; e += 4) {
        int c0 = col[e], c1 = col[e + 1], c2 = col[e + 2], c3 = col[e + 3];
        float w0 = w[e], w1 = w[e + 1], w2 = w[e + 2], w3 = w[e + 3];
        float x0 = __half2float(x[(size_t)c0 * DD + lane]);
        float x1 = __half2float(x[(size_t)c1 * DD + lane]);
        float x2 = __half2float(x[(size_t)c2 * DD + lane]);
        float x3 = __half2float(x[(size_t)c3 * DD + lane]);
        float d0 = dinv[c0], d1 = dinv[c1], d2 = dinv[c2], d3 = dinv[c3];
        accg += d0 * x0 + d1 * x1 + d2 * x2 + d3 * x3;
        acct += w0 * x0 + w1 * x1 + w2 * x2 + w3 * x3;
    }
    for (; e < e1; e++) {
        int c0 = col[e];
        float xv = __half2float(x[(size_t)c0 * DD + lane]);
        accg += dinv[c0] * xv;
        acct += w[e] * xv;
    }
    accg *= dinv[row_g];
    acct *= rsinv[r];
    float ss = acct * acct;
#pragma unroll
    for (int off = 32; off > 0; off >>= 1) ss += __shfl_xor(ss, off, 64);
    acct *= 1.0f / fmaxf(sqrtf(ss), 1e-12f);
    float zv = b2[lane];
#pragma unroll 8
    for (int l = 0; l < DD; l++) {
        float gl = __shfl(accg, l, 64);
        float tl = __shfl(acct, l, 64);
        zv += gl * Wg[l * DD + lane] + tl * Wt[l * DD + lane];
    }
    size_t oi = (size_t)row_g * DD + lane;
    gs[oi] = accg;
    ts[oi] = acct;
    zp[oi] = zv;
}

// ---------------- fused finalize (UU / II): g2 + t2 + gate + combine, 4x unrolled ----------
__global__ __launch_bounds__(512) void k_fused_fin(
        const int* __restrict__ rp, const int* __restrict__ col,
        const float* __restrict__ bw, const float* __restrict__ w,
        const float* __restrict__ rsinv,
        const float* __restrict__ W1, const float* __restrict__ W3,
        const __half* __restrict__ x, const float* __restrict__ gs,
        const float* __restrict__ ts, const float* __restrict__ zp,
        __half* __restrict__ xh_out, float* __restrict__ acc, int row_off, int nrows) {
    __shared__ float Wa[DD * DD];
    __shared__ float Wb[DD * DD];
    for (int i = threadIdx.x; i < DD * DD; i += 512) { Wa[i] = W1[i]; Wb[i] = W3[i]; }
    __syncthreads();
    int r = blockIdx.x * 8 + (threadIdx.x >> 6);
    int lane = threadIdx.x & 63;
    if (r >= nrows) return;
    int row_g = r + row_off;
    float accg = 0.f, acct = 0.f;
    int e = rp[r], e1 = rp[r + 1];
    for (; e + 4 <= e1; e += 4) {
        int c0 = col[e], c1 = col[e + 1], c2 = col[e + 2], c3 = col[e + 3];
        float b0 = bw[e], b1 = bw[e + 1], b2_ = bw[e + 2], b3 = bw[e + 3];
        float w0 = w[e], w1 = w[e + 1], w2 = w[e + 2], w3 = w[e + 3];
        float x0 = __half2float(x[(size_t)c0 * DD + lane]);
        float x1 = __half2float(x[(size_t)c1 * DD + lane]);
        float x2 = __half2float(x[(size_t)c2 * DD + lane]);
        float x3 = __half2float(x[(size_t)c3 * DD + lane]);
        accg += b0 * x0 + b1 * x1 + b2_ * x2 + b3 * x3;
        acct += w0 * x0 + w1 * x1 + w2 * x2 + w3 * x3;
    }
    for (; e < e1; e++) {
        int c0 = col[e];
        float xv = __half2float(x[(size_t)c0 * DD + lane]);
        accg += bw[e] * xv;
        acct += w[e] * xv;
    }
    acct *= rsinv[r];
    float ss = acct * acct;
#pragma unroll
    for (int off2 = 32; off2 > 0; off2 >>= 1) ss += __shfl_xor(ss, off2, 64);
    acct *= 1.0f / fmaxf(sqrtf(ss), 1e-12f);
    size_t oi = (size_t)row_g * DD + lane;
    float gfin = gs[oi] + accg;
    float tfin = ts[oi] + acct;
    float zv = zp[oi];
#pragma unroll 8
    for (int l = 0; l < DD; l++) {
        float gl = __shfl(gfin, l, 64);
        float tl = __shfl(tfin, l, 64);
        zv += gl * Wa[l * DD + lane] + tl * Wb[l * DD + lane];
    }
    float gate = 1.0f / (1.0f + __expf(-zv));
    float xn = gate * gfin + (1.0f - gate) * tfin;
    xh_out[oi] = __float2half(xn);
    acc[oi] += xn;
}

// ---------------- host launcher ----------------

extern "C" void kernel_launch(void* const* d_in, const int* in_sizes, int n_in,
                              void* d_out, int out_size, void* d_ws, size_t ws_size,
                              hipStream_t stream) {
    const float* user_emb = (const float*)d_in[0];
    const float* item_emb = (const float*)d_in[1];
    const float* intents  = (const float*)d_in[2];
    const float* W2       = (const float*)d_in[3];
    const float* b2       = (const float*)d_in[4];
    const float* uu_w     = (const float*)d_in[5];
    const float* ii_w     = (const float*)d_in[6];
    const int*   ui_u     = (const int*)d_in[7];
    const int*   ui_i     = (const int*)d_in[8];
    const int*   uu_h     = (const int*)d_in[9];
    const int*   uu_t     = (const int*)d_in[10];
    const int*   ii_h     = (const int*)d_in[11];
    const int*   ii_t     = (const int*)d_in[12];
    float* acc = (float*)d_out;

    char* pw = (char*)d_ws;
    auto allocb = [&](size_t nbytes) -> char* {
        char* r = pw;
        pw += (nbytes + 255) & ~(size_t)255;
        return r;
    };
    // persistent (~252 MB total)
    float* gs   = (float*)allocb((size_t)NN * DD * 4);
    float* ts   = (float*)allocb((size_t)NN * DD * 4);
    float* zp   = (float*)allocb((size_t)NN * DD * 4);
    __half* xh0 = (__half*)allocb((size_t)NN * DD * 2);
    __half* xh1 = (__half*)allocb((size_t)NN * DD * 2);
    __half* c   = (__half*)allocb((size_t)EUI * KK * 2);   // 64 MB; build-time scratch aliases here
    float* w    = (float*)allocb((size_t)EUI * 4);
    float* rs   = (float*)allocb((size_t)NU * 4);
    float* dinv = (float*)allocb((size_t)NN * 4);
    float* iuu  = (float*)allocb((size_t)NU * 4);
    float* iii  = (float*)allocb((size_t)NI * 4);
    float* Wd_g = (float*)allocb((size_t)DD * DD * 4);
    float* Wd_t = (float*)allocb((size_t)DD * DD * 4);
    int* rp_u   = (int*)allocb(((size_t)NU + 1) * 4);
    int* rp_i   = (int*)allocb(((size_t)NI + 1) * 4);
    int* rp_uu  = (int*)allocb(((size_t)NU + 1) * 4);
    int* rp_ii  = (int*)allocb(((size_t)NI + 1) * 4);
    int* headU  = (int*)allocb((size_t)EUI * 4);
    int* colU   = (int*)allocb((size_t)EUI * 4);
    int* colI   = (int*)allocb((size_t)EUI * 4);
    int* headUU = (int*)allocb((size_t)EUU * 4);
    int* colUU  = (int*)allocb((size_t)EUU * 4);
    int* headII = (int*)allocb((size_t)EII * 4);
    int* colII  = (int*)allocb((size_t)EII * 4);
    int* mUI    = (int*)allocb((size_t)EUI * 4);
    float* bwUU = (float*)allocb((size_t)EUU * 4);
    float* bwII = (float*)allocb((size_t)EII * 4);

    // build-time scratch aliased into c (all consumers finish before c is first written)
    char* ca = (char*)c;
    int* cur    = (int*)ca;                       ca += ((size_t)NU * 4 + 255) & ~(size_t)255;
    int* lst_u  = (int*)ca;                       ca += ((size_t)EUI * 4 + 255) & ~(size_t)255;
    int* lst_i  = (int*)ca;                       ca += ((size_t)EUI * 4 + 255) & ~(size_t)255;
    int* lst_uu = (int*)ca;                       ca += ((size_t)EUU * 4 + 255) & ~(size_t)255;
    int* lst_ii = (int*)ca;                       ca += ((size_t)EII * 4 + 255) & ~(size_t)255;
    int* posU   = (int*)ca;

    const int B = 256;

    auto build_csr = [&](const int* h, int E, int n, int* rp, int* lst) {
        hipMemsetAsync(cur, 0, (size_t)n * 4, stream);
        k_count<<<cdiv(E, B), B, 0, stream>>>(h, cur, E);
        k_scan<<<1, 1024, 0, stream>>>(cur, rp, n);
        hipMemsetAsync(cur, 0, (size_t)n * 4, stream);
        k_scatter<<<cdiv(E, B), B, 0, stream>>>(h, rp, cur, lst, E);
    };

    build_csr(ui_u, EUI, NU, rp_u, lst_u);
    build_csr(ui_i, EUI, NI, rp_i, lst_i);
    build_csr(uu_h, EUU, NU, rp_uu, lst_uu);
    build_csr(ii_h, EII, NI, rp_ii, lst_ii);
    k_dinv<<<cdiv(NN, B), B, 0, stream>>>(rp_u, rp_i, dinv);
    k_rowsum_inv<<<cdiv(NU, B), B, 0, stream>>>(rp_uu, lst_uu, uu_w, iuu, NU);
    k_rowsum_inv<<<cdiv(NI, B), B, 0, stream>>>(rp_ii, lst_ii, ii_w, iii, NI);
    k_build_ui<<<cdiv(EUI, B), B, 0, stream>>>(lst_u, ui_u, ui_i, headU, colU, EUI);
    k_build_colI<<<cdiv(EUI, B), B, 0, stream>>>(lst_i, ui_u, colI, EUI);
    k_posU<<<cdiv(EUI, B), B, 0, stream>>>(lst_u, posU, EUI);
    k_mapUI<<<cdiv(EUI, B), B, 0, stream>>>(lst_i, posU, mUI, EUI);
    k_build_s<<<cdiv(EUU, B), B, 0, stream>>>(lst_uu, uu_h, uu_t, uu_w, iuu, 0,
                                              headUU, colUU, bwUU, EUU);
    k_build_s<<<cdiv(EII, B), B, 0, stream>>>(lst_ii, ii_h, ii_t, ii_w, iii, NU,
                                              headII, colII, bwII, EII);
    k_wdiff<<<cdiv(DD * DD, B), B, 0, stream>>>(W2, Wd_g, Wd_t);
    k_init<<<cdiv((long)NN * DD, B), B, 0, stream>>>(user_emb, item_emb, xh0, acc);

    for (int layer = 0; layer < 2; ++layer) {
        const __half* xin = (layer == 0) ? xh0 : xh1;
        __half* xout = (layer == 0) ? xh1 : xh0;

        // ---- UI phase: passA (U-CSR order) -> per-side passBC + fused g1+t1+zpre ----
        k_passA<<<cdiv(EUI, B), B, 0, stream>>>(headU, colU, xin, intents, c, EUI);
        k_passBC<<<cdiv((long)NU * 8, B), B, 0, stream>>>(rp_u, nullptr, c, w, rs, NU);
        k_fused_ui<<<cdiv(NU, 8), 512, 0, stream>>>(rp_u, colU, w, rs, dinv, Wd_g, Wd_t,
                                                    b2, xin, gs, ts, zp, 0, NU);
        k_passBC<<<cdiv((long)NI * 8, B), B, 0, stream>>>(rp_i, mUI, c, w, rs, NI);
        k_fused_ui<<<cdiv(NI, 8), 512, 0, stream>>>(rp_i, colI, w, rs, dinv, Wd_g, Wd_t,
                                                    b2, xin, gs, ts, zp, NU, NI);

        // ---- UU: passA (CSR order) -> passBC (stream) -> finalize user rows ----
        k_passA<<<cdiv(EUU, B), B, 0, stream>>>(headUU, colUU, xin, intents, c, EUU);
        k_passBC<<<cdiv((long)NU * 8, B), B, 0, stream>>>(rp_uu, nullptr, c, w, rs, NU);
        k_fused_fin<<<cdiv(NU, 8), 512, 0, stream>>>(rp_uu, colUU, bwUU, w, rs,
                                                     W2 + DD * DD, W2 + 3 * DD * DD,
                                                     xin, gs, ts, zp, xout, acc, 0, NU);

        // ---- II: passA (CSR order) -> passBC (stream) -> finalize item rows ----
        k_passA<<<cdiv(EII, B), B, 0, stream>>>(headII, colII, xin, intents, c, EII);
        k_passBC<<<cdiv((long)NI * 8, B), B, 0, stream>>>(rp_ii, nullptr, c, w, rs, NI);
        k_fused_fin<<<cdiv(NI, 8), 512, 0, stream>>>(rp_ii, colII, bwII, w, rs,
                                                     W2 + DD * DD, W2 + 3 * DD * DD,
                                                     xin, gs, ts, zp, xout, acc, NU, NI);
    }
}

// Round 8
// 2828.581 us; speedup vs baseline: 1.1482x; 1.0005x over previous
//
#include <hip/hip_runtime.h>
#include <hip/hip_fp16.h>

#define NU 100000
#define NI 50000
#define NN 150000
#define DD 64
#define KK 32
#define EUI 1000000
#define EUU 500000
#define EII 500000

static inline int cdiv(long a, int b) { return (int)((a + b - 1) / b); }

// ---------------- CSR build ----------------

__global__ void k_count(const int* __restrict__ h, int* __restrict__ cnt, int E) {
    int e = blockIdx.x * blockDim.x + threadIdx.x;
    if (e < E) atomicAdd(&cnt[h[e]], 1);
}

__global__ __launch_bounds__(1024) void k_scan(const int* __restrict__ cnt,
                                               int* __restrict__ rp, int n) {
    __shared__ int wsum[16];
    __shared__ int carry_s;
    int tid = threadIdx.x;
    int lane = tid & 63, wid = tid >> 6;
    if (tid == 0) carry_s = 0;
    __syncthreads();
    for (int base = 0; base < n; base += 1024) {
        int i = base + tid;
        int v = (i < n) ? cnt[i] : 0;
        int s = v;
#pragma unroll
        for (int off = 1; off < 64; off <<= 1) {
            int t = __shfl_up(s, off, 64);
            if (lane >= off) s += t;
        }
        if (lane == 63) wsum[wid] = s;
        __syncthreads();
        int woff = 0, total = 0;
#pragma unroll
        for (int w = 0; w < 16; w++) { int ws = wsum[w]; total += ws; if (w < wid) woff += ws; }
        int carry = carry_s;
        if (i < n) rp[i] = carry + woff + (s - v);
        __syncthreads();
        if (tid == 0) carry_s = carry + total;
        __syncthreads();
    }
    if (tid == 0) rp[n] = carry_s;
}

__global__ void k_scatter(const int* __restrict__ h, const int* __restrict__ rp,
                          int* __restrict__ cur, int* __restrict__ lst, int E) {
    int e = blockIdx.x * blockDim.x + threadIdx.x;
    if (e >= E) return;
    int r = h[e];
    int p = rp[r] + atomicAdd(&cur[r], 1);
    lst[p] = e;
}

__global__ void k_dinv(const int* __restrict__ rpu, const int* __restrict__ rpi,
                       float* __restrict__ dinv) {
    int t = blockIdx.x * blockDim.x + threadIdx.x;
    if (t >= NN) return;
    int deg = (t < NU) ? rpu[t + 1] - rpu[t] : rpi[t - NU + 1] - rpi[t - NU];
    dinv[t] = deg > 0 ? rsqrtf((float)deg) : 0.0f;
}

__global__ void k_rowsum_inv(const int* __restrict__ rp, const int* __restrict__ lst,
                             const float* __restrict__ w, float* __restrict__ out, int n) {
    int r = blockIdx.x * blockDim.x + threadIdx.x;
    if (r >= n) return;
    float s = 0.f;
    int e1 = rp[r + 1];
    for (int e = rp[r]; e < e1; e++) s += w[lst[e]];
    out[r] = (s != 0.0f) ? 1.0f / s : 0.0f;
}

__global__ void k_wdiff(const float* __restrict__ W2, float* __restrict__ Wd_g,
                        float* __restrict__ Wd_t) {
    int i = blockIdx.x * blockDim.x + threadIdx.x;
    if (i >= DD * DD) return;
    Wd_g[i] = W2[i] - W2[DD * DD + i];
    Wd_t[i] = W2[2 * DD * DD + i] - W2[3 * DD * DD + i];
}

__global__ void k_init(const float* __restrict__ ue, const float* __restrict__ ie,
                       __half* __restrict__ xh, float* __restrict__ acc) {
    size_t i = (size_t)blockIdx.x * blockDim.x + threadIdx.x;
    if (i >= (size_t)NN * DD) return;
    float v = (i < (size_t)NU * DD) ? ue[i] : ie[i - (size_t)NU * DD];
    xh[i] = __float2half(v);
    acc[i] = v;
}

// ---------------- map-building kernels (x-independent, run once) ----------------

__global__ void k_posU(const int* __restrict__ lst, int* __restrict__ pos, int E) {
    int p = blockIdx.x * blockDim.x + threadIdx.x;
    if (p < E) pos[lst[p]] = p;
}

__global__ void k_mapUI(const int* __restrict__ lst_i, const int* __restrict__ posU,
                        int* __restrict__ mUI, int E) {
    int p = blockIdx.x * blockDim.x + threadIdx.x;
    if (p < E) mUI[p] = posU[lst_i[p]];
}

__global__ void k_build_ui(const int* __restrict__ lst_u, const int* __restrict__ ui_u,
                           const int* __restrict__ ui_i, int* __restrict__ headU,
                           int* __restrict__ colU, int E) {
    int p = blockIdx.x * blockDim.x + threadIdx.x;
    if (p >= E) return;
    int e = lst_u[p];
    headU[p] = ui_u[e];
    colU[p] = ui_i[e] + NU;
}

__global__ void k_build_colI(const int* __restrict__ lst_i, const int* __restrict__ ui_u,
                             int* __restrict__ colI, int E) {
    int p = blockIdx.x * blockDim.x + threadIdx.x;
    if (p < E) colI[p] = ui_u[lst_i[p]];
}

// gw[p] = dinv[row_g] * dinv[col[p]] for positions of row r (thread per row)
__global__ void k_build_gw(const int* __restrict__ rp, const int* __restrict__ col,
                           const float* __restrict__ dinv, int row_off,
                           float* __restrict__ gw, int n) {
    int r = blockIdx.x * blockDim.x + threadIdx.x;
    if (r >= n) return;
    float dh = dinv[r + row_off];
    int e1 = rp[r + 1];
    for (int p = rp[r]; p < e1; p++) gw[p] = dh * dinv[col[p]];
}

// single-sided: head/col as GLOBAL node indices, bw = normalized base weight (CSR order)
__global__ void k_build_s(const int* __restrict__ lst, const int* __restrict__ eh,
                          const int* __restrict__ et, const float* __restrict__ ew,
                          const float* __restrict__ inv, int off,
                          int* __restrict__ head, int* __restrict__ col,
                          float* __restrict__ bw, int E) {
    int p = blockIdx.x * blockDim.x + threadIdx.x;
    if (p >= E) return;
    int e = lst[p];
    int h = eh[e];
    head[p] = h + off;
    col[p] = et[e] + off;
    bw[p] = ew[e] * inv[h];
}

// ---------------- pass A (CSR order): c[p] = alpha * dist, fp16 ----------------

__global__ __launch_bounds__(256) void k_passA(
        const int* __restrict__ head, const int* __restrict__ col,
        const __half* __restrict__ x, const float* __restrict__ intents,
        __half* __restrict__ c_out, int E) {
    __shared__ float Wl[DD * KK];
    for (int idx = threadIdx.x; idx < DD * KK; idx += blockDim.x) Wl[idx] = intents[idx];
    __syncthreads();
    int p = blockIdx.x * blockDim.x + threadIdx.x;
    if (p >= E) return;
    const uint4* hp = (const uint4*)(x + (size_t)head[p] * DD);
    const uint4* tp = (const uint4*)(x + (size_t)col[p] * DD);
    uint4 hraw[8], traw[8];
#pragma unroll
    for (int j = 0; j < 8; j++) hraw[j] = hp[j];
#pragma unroll
    for (int j = 0; j < 8; j++) traw[j] = tp[j];
    const __half2* h2 = (const __half2*)hraw;
    const __half2* t2 = (const __half2*)traw;
    float logit[KK];
#pragma unroll
    for (int k = 0; k < KK; k++) logit[k] = 0.f;
    float dot = 0.f;
#pragma unroll 4
    for (int l4 = 0; l4 < 16; l4++) {
        float2 ha = __half22float2(h2[2 * l4]), hb = __half22float2(h2[2 * l4 + 1]);
        float2 ta = __half22float2(t2[2 * l4]), tb = __half22float2(t2[2 * l4 + 1]);
        float p0 = ha.x * ta.x, p1 = ha.y * ta.y, p2 = hb.x * tb.x, p3 = hb.y * tb.y;
        dot += p0 + p1 + p2 + p3;
        const float* w = &Wl[l4 * 4 * KK];
#pragma unroll
        for (int k = 0; k < KK; k++)
            logit[k] += p0 * w[k] + p1 * w[KK + k] + p2 * w[2 * KK + k] + p3 * w[3 * KK + k];
    }
    float m = logit[0];
#pragma unroll
    for (int k = 1; k < KK; k++) m = fmaxf(m, logit[k]);
    float ssum = 0.f;
#pragma unroll
    for (int k = 0; k < KK; k++) { float ev = __expf(logit[k] - m); logit[k] = ev; ssum += ev; }
    float scale = 0.5f * (dot + 1.0f) / ssum;
    uint4 pk[4];
    unsigned int* u = (unsigned int*)pk;
#pragma unroll
    for (int k2 = 0; k2 < 16; k2++) {
        __half2 hh = __floats2half2_rn(logit[2 * k2] * scale, logit[2 * k2 + 1] * scale);
        u[k2] = *reinterpret_cast<const unsigned int*>(&hh);
    }
    uint4* dst = (uint4*)(c_out + (size_t)p * KK);
#pragma unroll
    for (int q = 0; q < 4; q++) dst[q] = pk[q];
}

// ---------------- pass B+C: agg -> recip -> edge weights + inv rowsum ----------------
__global__ __launch_bounds__(256) void k_passBC(const int* __restrict__ rp,
                                                const int* __restrict__ map,
                                                const __half* __restrict__ c,
                                                float* __restrict__ w,
                                                float* __restrict__ rsinv, int n) {
    int gid = blockIdx.x * blockDim.x + threadIdx.x;
    int node = gid >> 3, j = gid & 7;
    if (node >= n) return;
    int p0 = rp[node], p1 = rp[node + 1];
    const uint2* cp = (const uint2*)c;
    float4 agg = make_float4(0.f, 0.f, 0.f, 0.f);
    for (int p = p0; p < p1; p++) {
        int idx = map ? map[p] : p;
        uint2 v = cp[(size_t)idx * 8 + j];
        float2 fa = __half22float2(*reinterpret_cast<const __half2*>(&v.x));
        float2 fb = __half22float2(*reinterpret_cast<const __half2*>(&v.y));
        agg.x += fa.x; agg.y += fa.y; agg.z += fb.x; agg.w += fb.y;
    }
    float4 rec;
    rec.x = (agg.x != 0.f) ? 1.f / agg.x : 0.f;
    rec.y = (agg.y != 0.f) ? 1.f / agg.y : 0.f;
    rec.z = (agg.z != 0.f) ? 1.f / agg.z : 0.f;
    rec.w = (agg.w != 0.f) ? 1.f / agg.w : 0.f;
    float rs = 0.f;
    for (int p = p0; p < p1; p++) {
        int idx = map ? map[p] : p;
        uint2 v = cp[(size_t)idx * 8 + j];
        float2 fa = __half22float2(*reinterpret_cast<const __half2*>(&v.x));
        float2 fb = __half22float2(*reinterpret_cast<const __half2*>(&v.y));
        float dot = fa.x * rec.x + fa.y * rec.y + fb.x * rec.z + fb.y * rec.w;
        dot += __shfl_xor(dot, 1, 64);
        dot += __shfl_xor(dot, 2, 64);
        dot += __shfl_xor(dot, 4, 64);
        float wv = dot * (1.0f / KK);
        if (j == 0) w[p] = wv;
        rs += wv;
    }
    if (j == 0) rsinv[node] = (rs != 0.f) ? 1.f / rs : 0.f;
}

// ---------------- fused UI: g1 + t1 + z-preact; dual-edge half-wave, 8 edges/iter --------
// packed layout: lane s=lane&31 holds dims (2s, 2s+1); halves process alternating edges.
__global__ __launch_bounds__(512) void k_fused_ui(
        const int* __restrict__ rp, const int* __restrict__ col,
        const float* __restrict__ gw, const float* __restrict__ w,
        const float* __restrict__ rsinv, const float* __restrict__ Wd_g,
        const float* __restrict__ Wd_t, const float* __restrict__ b2,
        const __half* __restrict__ x, float* __restrict__ gs, float* __restrict__ ts,
        float* __restrict__ zp, int row_off, int nrows) {
    __shared__ float Wg[DD * DD];
    __shared__ float Wt[DD * DD];
    for (int i = threadIdx.x; i < DD * DD; i += 512) { Wg[i] = Wd_g[i]; Wt[i] = Wd_t[i]; }
    __syncthreads();
    int r = blockIdx.x * 8 + (threadIdx.x >> 6);
    int lane = threadIdx.x & 63;
    int sub = lane & 31, half = lane >> 5;
    if (r >= nrows) return;
    int row_g = r + row_off;
    const __half2* x2 = (const __half2*)x;
    float gx = 0.f, gy = 0.f, tx = 0.f, ty = 0.f;
    int e = rp[r], e1 = rp[r + 1];
    for (; e + 8 <= e1; e += 8) {
#pragma unroll
        for (int u = 0; u < 4; u++) {
            int idx = e + 2 * u + half;
            int cc = col[idx];
            float wg = gw[idx], wt = w[idx];
            float2 xv = __half22float2(x2[(size_t)cc * 32 + sub]);
            gx += wg * xv.x; gy += wg * xv.y;
            tx += wt * xv.x; ty += wt * xv.y;
        }
    }
    for (; e < e1; e += 2) {
        int idx = e + half;
        if (idx < e1) {
            int cc = col[idx];
            float wg = gw[idx], wt = w[idx];
            float2 xv = __half22float2(x2[(size_t)cc * 32 + sub]);
            gx += wg * xv.x; gy += wg * xv.y;
            tx += wt * xv.x; ty += wt * xv.y;
        }
    }
    gx += __shfl_xor(gx, 32, 64); gy += __shfl_xor(gy, 32, 64);
    tx += __shfl_xor(tx, 32, 64); ty += __shfl_xor(ty, 32, 64);
    float rsv = rsinv[r];
    tx *= rsv; ty *= rsv;
    float ss = tx * tx + ty * ty;
#pragma unroll
    for (int off = 16; off > 0; off >>= 1) ss += __shfl_xor(ss, off, 64);
    float inv_n = 1.0f / fmaxf(sqrtf(ss), 1e-12f);
    tx *= inv_n; ty *= inv_n;
    float zv = b2[lane];
#pragma unroll
    for (int l = 0; l < DD; l++) {
        float gl = __shfl((l & 1) ? gy : gx, l >> 1, 64);
        float tl = __shfl((l & 1) ? ty : tx, l >> 1, 64);
        zv += gl * Wg[l * DD + lane] + tl * Wt[l * DD + lane];
    }
    // unpack to dim=lane layout for stores
    float ga = __shfl(gx, lane >> 1, 64), gb = __shfl(gy, lane >> 1, 64);
    float ta = __shfl(tx, lane >> 1, 64), tb = __shfl(ty, lane >> 1, 64);
    float gsv = (lane & 1) ? gb : ga;
    float tsv = (lane & 1) ? tb : ta;
    size_t oi = (size_t)row_g * DD + lane;
    gs[oi] = gsv;
    ts[oi] = tsv;
    zp[oi] = zv;
}

// ---------------- fused finalize (UU/II): g2 + t2 + gate + combine; dual-edge ----------
__global__ __launch_bounds__(512) void k_fused_fin(
        const int* __restrict__ rp, const int* __restrict__ col,
        const float* __restrict__ bw, const float* __restrict__ w,
        const float* __restrict__ rsinv,
        const float* __restrict__ W1, const float* __restrict__ W3,
        const __half* __restrict__ x, const float* __restrict__ gs,
        const float* __restrict__ ts, const float* __restrict__ zp,
        __half* __restrict__ xh_out, float* __restrict__ acc, int row_off, int nrows) {
    __shared__ float Wa[DD * DD];
    __shared__ float Wb[DD * DD];
    for (int i = threadIdx.x; i < DD * DD; i += 512) { Wa[i] = W1[i]; Wb[i] = W3[i]; }
    __syncthreads();
    int r = blockIdx.x * 8 + (threadIdx.x >> 6);
    int lane = threadIdx.x & 63;
    int sub = lane & 31, half = lane >> 5;
    if (r >= nrows) return;
    int row_g = r + row_off;
    const __half2* x2 = (const __half2*)x;
    float gx = 0.f, gy = 0.f, tx = 0.f, ty = 0.f;
    int e = rp[r], e1 = rp[r + 1];
    for (; e + 8 <= e1; e += 8) {
#pragma unroll
        for (int u = 0; u < 4; u++) {
            int idx = e + 2 * u + half;
            int cc = col[idx];
            float wg = bw[idx], wt = w[idx];
            float2 xv = __half22float2(x2[(size_t)cc * 32 + sub]);
            gx += wg * xv.x; gy += wg * xv.y;
            tx += wt * xv.x; ty += wt * xv.y;
        }
    }
    for (; e < e1; e += 2) {
        int idx = e + half;
        if (idx < e1) {
            int cc = col[idx];
            float wg = bw[idx], wt = w[idx];
            float2 xv = __half22float2(x2[(size_t)cc * 32 + sub]);
            gx += wg * xv.x; gy += wg * xv.y;
            tx += wt * xv.x; ty += wt * xv.y;
        }
    }
    gx += __shfl_xor(gx, 32, 64); gy += __shfl_xor(gy, 32, 64);
    tx += __shfl_xor(tx, 32, 64); ty += __shfl_xor(ty, 32, 64);
    float rsv = rsinv[r];
    tx *= rsv; ty *= rsv;
    float ss = tx * tx + ty * ty;
#pragma unroll
    for (int off = 16; off > 0; off >>= 1) ss += __shfl_xor(ss, off, 64);
    float inv_n = 1.0f / fmaxf(sqrtf(ss), 1e-12f);
    tx *= inv_n; ty *= inv_n;
    // add stored g1/t1 rows (packed float2 reads)
    float2 g0 = ((const float2*)(gs + (size_t)row_g * DD))[sub];
    float2 t0 = ((const float2*)(ts + (size_t)row_g * DD))[sub];
    float gfx = g0.x + gx, gfy = g0.y + gy;
    float tfx = t0.x + tx, tfy = t0.y + ty;
    size_t oi = (size_t)row_g * DD + lane;
    float zv = zp[oi];
#pragma unroll
    for (int l = 0; l < DD; l++) {
        float gl = __shfl((l & 1) ? gfy : gfx, l >> 1, 64);
        float tl = __shfl((l & 1) ? tfy : tfx, l >> 1, 64);
        zv += gl * Wa[l * DD + lane] + tl * Wb[l * DD + lane];
    }
    float ga = __shfl(gfx, lane >> 1, 64), gb = __shfl(gfy, lane >> 1, 64);
    float ta = __shfl(tfx, lane >> 1, 64), tb = __shfl(tfy, lane >> 1, 64);
    float gfin = (lane & 1) ? gb : ga;
    float tfin = (lane & 1) ? tb : ta;
    float gate = 1.0f / (1.0f + __expf(-zv));
    float xn = gate * gfin + (1.0f - gate) * tfin;
    xh_out[oi] = __float2half(xn);
    acc[oi] += xn;
}

// ---------------- host launcher ----------------

extern "C" void kernel_launch(void* const* d_in, const int* in_sizes, int n_in,
                              void* d_out, int out_size, void* d_ws, size_t ws_size,
                              hipStream_t stream) {
    const float* user_emb = (const float*)d_in[0];
    const float* item_emb = (const float*)d_in[1];
    const float* intents  = (const float*)d_in[2];
    const float* W2       = (const float*)d_in[3];
    const float* b2       = (const float*)d_in[4];
    const float* uu_w     = (const float*)d_in[5];
    const float* ii_w     = (const float*)d_in[6];
    const int*   ui_u     = (const int*)d_in[7];
    const int*   ui_i     = (const int*)d_in[8];
    const int*   uu_h     = (const int*)d_in[9];
    const int*   uu_t     = (const int*)d_in[10];
    const int*   ii_h     = (const int*)d_in[11];
    const int*   ii_t     = (const int*)d_in[12];
    float* acc = (float*)d_out;

    char* pw = (char*)d_ws;
    auto allocb = [&](size_t nbytes) -> char* {
        char* r = pw;
        pw += (nbytes + 255) & ~(size_t)255;
        return r;
    };
    // persistent (~260 MB total)
    float* gs   = (float*)allocb((size_t)NN * DD * 4);
    float* ts   = (float*)allocb((size_t)NN * DD * 4);
    float* zp   = (float*)allocb((size_t)NN * DD * 4);
    __half* xh0 = (__half*)allocb((size_t)NN * DD * 2);
    __half* xh1 = (__half*)allocb((size_t)NN * DD * 2);
    __half* c   = (__half*)allocb((size_t)EUI * KK * 2);   // 64 MB; build-time scratch aliases here
    float* w    = (float*)allocb((size_t)EUI * 4);
    float* rs   = (float*)allocb((size_t)NU * 4);
    float* dinv = (float*)allocb((size_t)NN * 4);
    float* iuu  = (float*)allocb((size_t)NU * 4);
    float* iii  = (float*)allocb((size_t)NI * 4);
    float* Wd_g = (float*)allocb((size_t)DD * DD * 4);
    float* Wd_t = (float*)allocb((size_t)DD * DD * 4);
    int* rp_u   = (int*)allocb(((size_t)NU + 1) * 4);
    int* rp_i   = (int*)allocb(((size_t)NI + 1) * 4);
    int* rp_uu  = (int*)allocb(((size_t)NU + 1) * 4);
    int* rp_ii  = (int*)allocb(((size_t)NI + 1) * 4);
    int* headU  = (int*)allocb((size_t)EUI * 4);
    int* colU   = (int*)allocb((size_t)EUI * 4);
    int* colI   = (int*)allocb((size_t)EUI * 4);
    int* headUU = (int*)allocb((size_t)EUU * 4);
    int* colUU  = (int*)allocb((size_t)EUU * 4);
    int* headII = (int*)allocb((size_t)EII * 4);
    int* colII  = (int*)allocb((size_t)EII * 4);
    int* mUI    = (int*)allocb((size_t)EUI * 4);
    float* bwUU = (float*)allocb((size_t)EUU * 4);
    float* bwII = (float*)allocb((size_t)EII * 4);
    float* gwU  = (float*)allocb((size_t)EUI * 4);
    float* gwI  = (float*)allocb((size_t)EUI * 4);

    // build-time scratch aliased into c (all consumers finish before c is first written)
    char* ca = (char*)c;
    int* cur    = (int*)ca;                       ca += ((size_t)NU * 4 + 255) & ~(size_t)255;
    int* lst_u  = (int*)ca;                       ca += ((size_t)EUI * 4 + 255) & ~(size_t)255;
    int* lst_i  = (int*)ca;                       ca += ((size_t)EUI * 4 + 255) & ~(size_t)255;
    int* lst_uu = (int*)ca;                       ca += ((size_t)EUU * 4 + 255) & ~(size_t)255;
    int* lst_ii = (int*)ca;                       ca += ((size_t)EII * 4 + 255) & ~(size_t)255;
    int* posU   = (int*)ca;

    const int B = 256;

    auto build_csr = [&](const int* h, int E, int n, int* rp, int* lst) {
        hipMemsetAsync(cur, 0, (size_t)n * 4, stream);
        k_count<<<cdiv(E, B), B, 0, stream>>>(h, cur, E);
        k_scan<<<1, 1024, 0, stream>>>(cur, rp, n);
        hipMemsetAsync(cur, 0, (size_t)n * 4, stream);
        k_scatter<<<cdiv(E, B), B, 0, stream>>>(h, rp, cur, lst, E);
    };

    build_csr(ui_u, EUI, NU, rp_u, lst_u);
    build_csr(ui_i, EUI, NI, rp_i, lst_i);
    build_csr(uu_h, EUU, NU, rp_uu, lst_uu);
    build_csr(ii_h, EII, NI, rp_ii, lst_ii);
    k_dinv<<<cdiv(NN, B), B, 0, stream>>>(rp_u, rp_i, dinv);
    k_rowsum_inv<<<cdiv(NU, B), B, 0, stream>>>(rp_uu, lst_uu, uu_w, iuu, NU);
    k_rowsum_inv<<<cdiv(NI, B), B, 0, stream>>>(rp_ii, lst_ii, ii_w, iii, NI);
    k_build_ui<<<cdiv(EUI, B), B, 0, stream>>>(lst_u, ui_u, ui_i, headU, colU, EUI);
    k_build_colI<<<cdiv(EUI, B), B, 0, stream>>>(lst_i, ui_u, colI, EUI);
    k_posU<<<cdiv(EUI, B), B, 0, stream>>>(lst_u, posU, EUI);
    k_mapUI<<<cdiv(EUI, B), B, 0, stream>>>(lst_i, posU, mUI, EUI);
    k_build_s<<<cdiv(EUU, B), B, 0, stream>>>(lst_uu, uu_h, uu_t, uu_w, iuu, 0,
                                              headUU, colUU, bwUU, EUU);
    k_build_s<<<cdiv(EII, B), B, 0, stream>>>(lst_ii, ii_h, ii_t, ii_w, iii, NU,
                                              headII, colII, bwII, EII);
    k_build_gw<<<cdiv(NU, B), B, 0, stream>>>(rp_u, colU, dinv, 0, gwU, NU);
    k_build_gw<<<cdiv(NI, B), B, 0, stream>>>(rp_i, colI, dinv, NU, gwI, NI);
    k_wdiff<<<cdiv(DD * DD, B), B, 0, stream>>>(W2, Wd_g, Wd_t);
    k_init<<<cdiv((long)NN * DD, B), B, 0, stream>>>(user_emb, item_emb, xh0, acc);

    for (int layer = 0; layer < 2; ++layer) {
        const __half* xin = (layer == 0) ? xh0 : xh1;
        __half* xout = (layer == 0) ? xh1 : xh0;

        // ---- UI phase: passA (U-CSR order) -> per-side passBC + fused g1+t1+zpre ----
        k_passA<<<cdiv(EUI, B), B, 0, stream>>>(headU, colU, xin, intents, c, EUI);
        k_passBC<<<cdiv((long)NU * 8, B), B, 0, stream>>>(rp_u, nullptr, c, w, rs, NU);
        k_fused_ui<<<cdiv(NU, 8), 512, 0, stream>>>(rp_u, colU, gwU, w, rs, Wd_g, Wd_t,
                                                    b2, xin, gs, ts, zp, 0, NU);
        k_passBC<<<cdiv((long)NI * 8, B), B, 0, stream>>>(rp_i, mUI, c, w, rs, NI);
        k_fused_ui<<<cdiv(NI, 8), 512, 0, stream>>>(rp_i, colI, gwI, w, rs, Wd_g, Wd_t,
                                                    b2, xin, gs, ts, zp, NU, NI);

        // ---- UU: passA (CSR order) -> passBC (stream) -> finalize user rows ----
        k_passA<<<cdiv(EUU, B), B, 0, stream>>>(headUU, colUU, xin, intents, c, EUU);
        k_passBC<<<cdiv((long)NU * 8, B), B, 0, stream>>>(rp_uu, nullptr, c, w, rs, NU);
        k_fused_fin<<<cdiv(NU, 8), 512, 0, stream>>>(rp_uu, colUU, bwUU, w, rs,
                                                     W2 + DD * DD, W2 + 3 * DD * DD,
                                                     xin, gs, ts, zp, xout, acc, 0, NU);

        // ---- II: passA (CSR order) -> passBC (stream) -> finalize item rows ----
        k_passA<<<cdiv(EII, B), B, 0, stream>>>(headII, colII, xin, intents, c, EII);
        k_passBC<<<cdiv((long)NI * 8, B), B, 0, stream>>>(rp_ii, nullptr, c, w, rs, NI);
        k_fused_fin<<<cdiv(NI, 8), 512, 0, stream>>>(rp_ii, colII, bwII, w, rs,
                                                     W2 + DD * DD, W2 + 3 * DD * DD,
                                                     xin, gs, ts, zp, xout, acc, NU, NI);
    }
}

// Round 9
// 2777.245 us; speedup vs baseline: 1.1695x; 1.0185x over previous
//
#include <hip/hip_runtime.h>
#include <hip/hip_fp16.h>

#define NU 100000
#define NI 50000
#define NN 150000
#define DD 64
#define KK 32
#define EUI 1000000
#define EUU 500000
#define EII 500000

static inline int cdiv(long a, int b) { return (int)((a + b - 1) / b); }

// ---------------- CSR build ----------------

__global__ void k_count(const int* __restrict__ h, int* __restrict__ cnt, int E) {
    int e = blockIdx.x * blockDim.x + threadIdx.x;
    if (e < E) atomicAdd(&cnt[h[e]], 1);
}

__global__ __launch_bounds__(1024) void k_scan(const int* __restrict__ cnt,
                                               int* __restrict__ rp, int n) {
    __shared__ int wsum[16];
    __shared__ int carry_s;
    int tid = threadIdx.x;
    int lane = tid & 63, wid = tid >> 6;
    if (tid == 0) carry_s = 0;
    __syncthreads();
    for (int base = 0; base < n; base += 1024) {
        int i = base + tid;
        int v = (i < n) ? cnt[i] : 0;
        int s = v;
#pragma unroll
        for (int off = 1; off < 64; off <<= 1) {
            int t = __shfl_up(s, off, 64);
            if (lane >= off) s += t;
        }
        if (lane == 63) wsum[wid] = s;
        __syncthreads();
        int woff = 0, total = 0;
#pragma unroll
        for (int w = 0; w < 16; w++) { int ws = wsum[w]; total += ws; if (w < wid) woff += ws; }
        int carry = carry_s;
        if (i < n) rp[i] = carry + woff + (s - v);
        __syncthreads();
        if (tid == 0) carry_s = carry + total;
        __syncthreads();
    }
    if (tid == 0) rp[n] = carry_s;
}

__global__ void k_scatter(const int* __restrict__ h, const int* __restrict__ rp,
                          int* __restrict__ cur, int* __restrict__ lst, int E) {
    int e = blockIdx.x * blockDim.x + threadIdx.x;
    if (e >= E) return;
    int r = h[e];
    int p = rp[r] + atomicAdd(&cur[r], 1);
    lst[p] = e;
}

__global__ void k_dinv(const int* __restrict__ rpu, const int* __restrict__ rpi,
                       float* __restrict__ dinv) {
    int t = blockIdx.x * blockDim.x + threadIdx.x;
    if (t >= NN) return;
    int deg = (t < NU) ? rpu[t + 1] - rpu[t] : rpi[t - NU + 1] - rpi[t - NU];
    dinv[t] = deg > 0 ? rsqrtf((float)deg) : 0.0f;
}

__global__ void k_rowsum_inv(const int* __restrict__ rp, const int* __restrict__ lst,
                             const float* __restrict__ w, float* __restrict__ out, int n) {
    int r = blockIdx.x * blockDim.x + threadIdx.x;
    if (r >= n) return;
    float s = 0.f;
    int e1 = rp[r + 1];
    for (int e = rp[r]; e < e1; e++) s += w[lst[e]];
    out[r] = (s != 0.0f) ? 1.0f / s : 0.0f;
}

__global__ void k_wdiff(const float* __restrict__ W2, float* __restrict__ Wd_g,
                        float* __restrict__ Wd_t) {
    int i = blockIdx.x * blockDim.x + threadIdx.x;
    if (i >= DD * DD) return;
    Wd_g[i] = W2[i] - W2[DD * DD + i];
    Wd_t[i] = W2[2 * DD * DD + i] - W2[3 * DD * DD + i];
}

__global__ void k_init(const float* __restrict__ ue, const float* __restrict__ ie,
                       __half* __restrict__ xh, float* __restrict__ acc) {
    size_t i = (size_t)blockIdx.x * blockDim.x + threadIdx.x;
    if (i >= (size_t)NN * DD) return;
    float v = (i < (size_t)NU * DD) ? ue[i] : ie[i - (size_t)NU * DD];
    xh[i] = __float2half(v);
    acc[i] = v;
}

// ---------------- map-building kernels (x-independent, run once) ----------------

__global__ void k_posU(const int* __restrict__ lst, int* __restrict__ pos, int E) {
    int p = blockIdx.x * blockDim.x + threadIdx.x;
    if (p < E) pos[lst[p]] = p;
}

__global__ void k_mapUI(const int* __restrict__ lst_i, const int* __restrict__ posU,
                        int* __restrict__ mUI, int E) {
    int p = blockIdx.x * blockDim.x + threadIdx.x;
    if (p < E) mUI[p] = posU[lst_i[p]];
}

__global__ void k_build_ui(const int* __restrict__ lst_u, const int* __restrict__ ui_u,
                           const int* __restrict__ ui_i, int* __restrict__ headU,
                           int* __restrict__ colUI, int E) {
    int p = blockIdx.x * blockDim.x + threadIdx.x;
    if (p >= E) return;
    int e = lst_u[p];
    headU[p] = ui_u[e];
    colUI[p] = ui_i[e] + NU;
}

__global__ void k_build_colI(const int* __restrict__ lst_i, const int* __restrict__ ui_u,
                             int* __restrict__ colUI, int E) {
    int p = blockIdx.x * blockDim.x + threadIdx.x;
    if (p < E) colUI[EUI + p] = ui_u[lst_i[p]];
}

// rp_ui = concat(rp_u, rp_i+EUI); rp_s = concat(rp_uu, rp_ii+EUU)
__global__ void k_build_rp2(const int* __restrict__ rp_u, const int* __restrict__ rp_i,
                            const int* __restrict__ rp_uu, const int* __restrict__ rp_ii,
                            int* __restrict__ rp_ui, int* __restrict__ rp_s) {
    int t = blockIdx.x * blockDim.x + threadIdx.x;
    if (t > NN) return;
    rp_ui[t] = (t <= NU) ? rp_u[t] : rp_i[t - NU] + EUI;
    rp_s[t]  = (t <= NU) ? rp_uu[t] : rp_ii[t - NU] + EUU;
}

// gw[p] = dinv[row] * dinv[col[p]] over all NN rows of rp_ui
__global__ void k_build_gw(const int* __restrict__ rp, const int* __restrict__ col,
                           const float* __restrict__ dinv, float* __restrict__ gw, int n) {
    int r = blockIdx.x * blockDim.x + threadIdx.x;
    if (r >= n) return;
    float dh = dinv[r];
    int e1 = rp[r + 1];
    for (int p = rp[r]; p < e1; p++) gw[p] = dh * dinv[col[p]];
}

// single-sided: positions offset by peo; node ids offset by off; bw pre-normalized
__global__ void k_build_s(const int* __restrict__ lst, const int* __restrict__ eh,
                          const int* __restrict__ et, const float* __restrict__ ew,
                          const float* __restrict__ inv, int off, int peo,
                          int* __restrict__ head, int* __restrict__ col,
                          float* __restrict__ bw, int E) {
    int p = blockIdx.x * blockDim.x + threadIdx.x;
    if (p >= E) return;
    int e = lst[p];
    int h = eh[e];
    head[peo + p] = h + off;
    col[peo + p] = et[e] + off;
    bw[peo + p] = ew[e] * inv[h];
}

// ---------------- pass A (CSR order): c[p] = alpha * dist, fp16 ----------------

__global__ __launch_bounds__(256) void k_passA(
        const int* __restrict__ head, const int* __restrict__ col,
        const __half* __restrict__ x, const float* __restrict__ intents,
        __half* __restrict__ c_out, int E) {
    __shared__ float Wl[DD * KK];
    for (int idx = threadIdx.x; idx < DD * KK; idx += blockDim.x) Wl[idx] = intents[idx];
    __syncthreads();
    int p = blockIdx.x * blockDim.x + threadIdx.x;
    if (p >= E) return;
    const uint4* hp = (const uint4*)(x + (size_t)head[p] * DD);
    const uint4* tp = (const uint4*)(x + (size_t)col[p] * DD);
    uint4 hraw[8], traw[8];
#pragma unroll
    for (int j = 0; j < 8; j++) hraw[j] = hp[j];
#pragma unroll
    for (int j = 0; j < 8; j++) traw[j] = tp[j];
    const __half2* h2 = (const __half2*)hraw;
    const __half2* t2 = (const __half2*)traw;
    float logit[KK];
#pragma unroll
    for (int k = 0; k < KK; k++) logit[k] = 0.f;
    float dot = 0.f;
#pragma unroll 4
    for (int l4 = 0; l4 < 16; l4++) {
        float2 ha = __half22float2(h2[2 * l4]), hb = __half22float2(h2[2 * l4 + 1]);
        float2 ta = __half22float2(t2[2 * l4]), tb = __half22float2(t2[2 * l4 + 1]);
        float p0 = ha.x * ta.x, p1 = ha.y * ta.y, p2 = hb.x * tb.x, p3 = hb.y * tb.y;
        dot += p0 + p1 + p2 + p3;
        const float* w = &Wl[l4 * 4 * KK];
#pragma unroll
        for (int k = 0; k < KK; k++)
            logit[k] += p0 * w[k] + p1 * w[KK + k] + p2 * w[2 * KK + k] + p3 * w[3 * KK + k];
    }
    float m = logit[0];
#pragma unroll
    for (int k = 1; k < KK; k++) m = fmaxf(m, logit[k]);
    float ssum = 0.f;
#pragma unroll
    for (int k = 0; k < KK; k++) { float ev = __expf(logit[k] - m); logit[k] = ev; ssum += ev; }
    float scale = 0.5f * (dot + 1.0f) / ssum;
    uint4 pk[4];
    unsigned int* u = (unsigned int*)pk;
#pragma unroll
    for (int k2 = 0; k2 < 16; k2++) {
        __half2 hh = __floats2half2_rn(logit[2 * k2] * scale, logit[2 * k2 + 1] * scale);
        u[k2] = *reinterpret_cast<const unsigned int*>(&hh);
    }
    uint4* dst = (uint4*)(c_out + (size_t)p * KK);
#pragma unroll
    for (int q = 0; q < 4; q++) dst[q] = pk[q];
}

// ---------------- pass B+C over all NN nodes ----------------
// idx = (node < nsplit) ? p : map[p - peoff]; map==nullptr -> stream.
__global__ __launch_bounds__(256) void k_passBC(const int* __restrict__ rp,
                                                const int* __restrict__ map,
                                                int nsplit, int peoff,
                                                const __half* __restrict__ c,
                                                float* __restrict__ w,
                                                float* __restrict__ rsinv, int n) {
    int gid = blockIdx.x * blockDim.x + threadIdx.x;
    int node = gid >> 3, j = gid & 7;
    if (node >= n) return;
    bool use_map = (map != nullptr) && (node >= nsplit);
    int p0 = rp[node], p1 = rp[node + 1];
    const uint2* cp = (const uint2*)c;
    float4 agg = make_float4(0.f, 0.f, 0.f, 0.f);
    for (int p = p0; p < p1; p++) {
        int idx = use_map ? map[p - peoff] : p;
        uint2 v = cp[(size_t)idx * 8 + j];
        float2 fa = __half22float2(*reinterpret_cast<const __half2*>(&v.x));
        float2 fb = __half22float2(*reinterpret_cast<const __half2*>(&v.y));
        agg.x += fa.x; agg.y += fa.y; agg.z += fb.x; agg.w += fb.y;
    }
    float4 rec;
    rec.x = (agg.x != 0.f) ? 1.f / agg.x : 0.f;
    rec.y = (agg.y != 0.f) ? 1.f / agg.y : 0.f;
    rec.z = (agg.z != 0.f) ? 1.f / agg.z : 0.f;
    rec.w = (agg.w != 0.f) ? 1.f / agg.w : 0.f;
    float rs = 0.f;
    for (int p = p0; p < p1; p++) {
        int idx = use_map ? map[p - peoff] : p;
        uint2 v = cp[(size_t)idx * 8 + j];
        float2 fa = __half22float2(*reinterpret_cast<const __half2*>(&v.x));
        float2 fb = __half22float2(*reinterpret_cast<const __half2*>(&v.y));
        float dot = fa.x * rec.x + fa.y * rec.y + fb.x * rec.z + fb.y * rec.w;
        dot += __shfl_xor(dot, 1, 64);
        dot += __shfl_xor(dot, 2, 64);
        dot += __shfl_xor(dot, 4, 64);
        float wv = dot * (1.0f / KK);
        if (j == 0) w[p] = wv;
        rs += wv;
    }
    if (j == 0) rsinv[node] = (rs != 0.f) ? 1.f / rs : 0.f;
}

// helper: broadcast packed component (l compile-time in unrolled loops)
#define PSHFL(a0, a1, a2, a3, l) \
    __shfl(((l) & 3) == 0 ? (a0) : ((l) & 3) == 1 ? (a1) : ((l) & 3) == 2 ? (a2) : (a3), (l) >> 2, 64)

// ---------------- fused UI over all NN rows: g1 + t1 + z-preact ----------------
// quarter-wave: 16-lane group per edge; lane sub=lane&15 holds dims 4sub..4sub+3.
__global__ __launch_bounds__(512) void k_fused_ui(
        const int* __restrict__ rp, const int* __restrict__ col,
        const float* __restrict__ gw, const float* __restrict__ w,
        const float* __restrict__ rsinv, const float* __restrict__ Wd_g,
        const float* __restrict__ Wd_t, const float* __restrict__ b2,
        const __half* __restrict__ x, float* __restrict__ gs, float* __restrict__ ts,
        float* __restrict__ zp, int nrows) {
    __shared__ float Wg[DD * DD];
    __shared__ float Wt[DD * DD];
    for (int i = threadIdx.x; i < DD * DD; i += 512) { Wg[i] = Wd_g[i]; Wt[i] = Wd_t[i]; }
    __syncthreads();
    int r = blockIdx.x * 8 + (threadIdx.x >> 6);
    int lane = threadIdx.x & 63;
    int sub = lane & 15, grp = lane >> 4;
    if (r >= nrows) return;
    const uint2* xq = (const uint2*)x;   // 8 B = 4 halfs per lane
    float g0 = 0, g1 = 0, g2 = 0, g3 = 0, t0 = 0, t1 = 0, t2 = 0, t3 = 0;
    int e = rp[r], e1 = rp[r + 1];
    for (; e + 8 <= e1; e += 8) {
#pragma unroll
        for (int u = 0; u < 2; u++) {
            int idx = e + 4 * u + grp;
            int cc = col[idx];
            float wg = gw[idx], wt = w[idx];
            uint2 raw = xq[(size_t)cc * 16 + sub];
            float2 xa = __half22float2(*(const __half2*)&raw.x);
            float2 xb = __half22float2(*(const __half2*)&raw.y);
            g0 += wg * xa.x; g1 += wg * xa.y; g2 += wg * xb.x; g3 += wg * xb.y;
            t0 += wt * xa.x; t1 += wt * xa.y; t2 += wt * xb.x; t3 += wt * xb.y;
        }
    }
    for (; e < e1; e += 4) {
        int idx = e + grp;
        if (idx < e1) {
            int cc = col[idx];
            float wg = gw[idx], wt = w[idx];
            uint2 raw = xq[(size_t)cc * 16 + sub];
            float2 xa = __half22float2(*(const __half2*)&raw.x);
            float2 xb = __half22float2(*(const __half2*)&raw.y);
            g0 += wg * xa.x; g1 += wg * xa.y; g2 += wg * xb.x; g3 += wg * xb.y;
            t0 += wt * xa.x; t1 += wt * xa.y; t2 += wt * xb.x; t3 += wt * xb.y;
        }
    }
#pragma unroll
    for (int off = 16; off <= 32; off <<= 1) {
        g0 += __shfl_xor(g0, off, 64); g1 += __shfl_xor(g1, off, 64);
        g2 += __shfl_xor(g2, off, 64); g3 += __shfl_xor(g3, off, 64);
        t0 += __shfl_xor(t0, off, 64); t1 += __shfl_xor(t1, off, 64);
        t2 += __shfl_xor(t2, off, 64); t3 += __shfl_xor(t3, off, 64);
    }
    float rsv = rsinv[r];
    t0 *= rsv; t1 *= rsv; t2 *= rsv; t3 *= rsv;
    float ss = t0 * t0 + t1 * t1 + t2 * t2 + t3 * t3;
    ss += __shfl_xor(ss, 1, 64); ss += __shfl_xor(ss, 2, 64);
    ss += __shfl_xor(ss, 4, 64); ss += __shfl_xor(ss, 8, 64);
    float inv_n = 1.0f / fmaxf(sqrtf(ss), 1e-12f);
    t0 *= inv_n; t1 *= inv_n; t2 *= inv_n; t3 *= inv_n;
    float zv = b2[lane];
#pragma unroll
    for (int l = 0; l < DD; l++) {
        float gl = PSHFL(g0, g1, g2, g3, l);
        float tl = PSHFL(t0, t1, t2, t3, l);
        zv += gl * Wg[l * DD + lane] + tl * Wt[l * DD + lane];
    }
    // dim=lane layout for stores
    float ga0 = __shfl(g0, lane >> 2, 64), ga1 = __shfl(g1, lane >> 2, 64);
    float ga2 = __shfl(g2, lane >> 2, 64), ga3 = __shfl(g3, lane >> 2, 64);
    float ta0 = __shfl(t0, lane >> 2, 64), ta1 = __shfl(t1, lane >> 2, 64);
    float ta2 = __shfl(t2, lane >> 2, 64), ta3 = __shfl(t3, lane >> 2, 64);
    int j = lane & 3;
    float gsv = j == 0 ? ga0 : j == 1 ? ga1 : j == 2 ? ga2 : ga3;
    float tsv = j == 0 ? ta0 : j == 1 ? ta1 : j == 2 ? ta2 : ta3;
    size_t oi = (size_t)r * DD + lane;
    gs[oi] = gsv;
    ts[oi] = tsv;
    zp[oi] = zv;
}

// ---------------- fused finalize over all NN rows: g2 + t2 + gate + combine ------------
__global__ __launch_bounds__(512) void k_fused_fin(
        const int* __restrict__ rp, const int* __restrict__ col,
        const float* __restrict__ bw, const float* __restrict__ w,
        const float* __restrict__ rsinv,
        const float* __restrict__ W1, const float* __restrict__ W3,
        const __half* __restrict__ x, const float* __restrict__ gs,
        const float* __restrict__ ts, const float* __restrict__ zp,
        __half* __restrict__ xh_out, float* __restrict__ acc, int nrows) {
    __shared__ float Wa[DD * DD];
    __shared__ float Wb[DD * DD];
    for (int i = threadIdx.x; i < DD * DD; i += 512) { Wa[i] = W1[i]; Wb[i] = W3[i]; }
    __syncthreads();
    int r = blockIdx.x * 8 + (threadIdx.x >> 6);
    int lane = threadIdx.x & 63;
    int sub = lane & 15, grp = lane >> 4;
    if (r >= nrows) return;
    const uint2* xq = (const uint2*)x;
    float g0 = 0, g1 = 0, g2 = 0, g3 = 0, t0 = 0, t1 = 0, t2 = 0, t3 = 0;
    int e = rp[r], e1 = rp[r + 1];
    for (; e + 8 <= e1; e += 8) {
#pragma unroll
        for (int u = 0; u < 2; u++) {
            int idx = e + 4 * u + grp;
            int cc = col[idx];
            float wg = bw[idx], wt = w[idx];
            uint2 raw = xq[(size_t)cc * 16 + sub];
            float2 xa = __half22float2(*(const __half2*)&raw.x);
            float2 xb = __half22float2(*(const __half2*)&raw.y);
            g0 += wg * xa.x; g1 += wg * xa.y; g2 += wg * xb.x; g3 += wg * xb.y;
            t0 += wt * xa.x; t1 += wt * xa.y; t2 += wt * xb.x; t3 += wt * xb.y;
        }
    }
    for (; e < e1; e += 4) {
        int idx = e + grp;
        if (idx < e1) {
            int cc = col[idx];
            float wg = bw[idx], wt = w[idx];
            uint2 raw = xq[(size_t)cc * 16 + sub];
            float2 xa = __half22float2(*(const __half2*)&raw.x);
            float2 xb = __half22float2(*(const __half2*)&raw.y);
            g0 += wg * xa.x; g1 += wg * xa.y; g2 += wg * xb.x; g3 += wg * xb.y;
            t0 += wt * xa.x; t1 += wt * xa.y; t2 += wt * xb.x; t3 += wt * xb.y;
        }
    }
#pragma unroll
    for (int off = 16; off <= 32; off <<= 1) {
        g0 += __shfl_xor(g0, off, 64); g1 += __shfl_xor(g1, off, 64);
        g2 += __shfl_xor(g2, off, 64); g3 += __shfl_xor(g3, off, 64);
        t0 += __shfl_xor(t0, off, 64); t1 += __shfl_xor(t1, off, 64);
        t2 += __shfl_xor(t2, off, 64); t3 += __shfl_xor(t3, off, 64);
    }
    float rsv = rsinv[r];
    t0 *= rsv; t1 *= rsv; t2 *= rsv; t3 *= rsv;
    float ss = t0 * t0 + t1 * t1 + t2 * t2 + t3 * t3;
    ss += __shfl_xor(ss, 1, 64); ss += __shfl_xor(ss, 2, 64);
    ss += __shfl_xor(ss, 4, 64); ss += __shfl_xor(ss, 8, 64);
    float inv_n = 1.0f / fmaxf(sqrtf(ss), 1e-12f);
    t0 *= inv_n; t1 *= inv_n; t2 *= inv_n; t3 *= inv_n;
    // add stored g1/t1 rows (float4 packed reads match 4-dims/lane layout)
    float4 gp = ((const float4*)(gs + (size_t)r * DD))[sub];
    float4 tp = ((const float4*)(ts + (size_t)r * DD))[sub];
    float gf0 = gp.x + g0, gf1 = gp.y + g1, gf2 = gp.z + g2, gf3 = gp.w + g3;
    float tf0 = tp.x + t0, tf1 = tp.y + t1, tf2 = tp.z + t2, tf3 = tp.w + t3;
    size_t oi = (size_t)r * DD + lane;
    float zv = zp[oi];
#pragma unroll
    for (int l = 0; l < DD; l++) {
        float gl = PSHFL(gf0, gf1, gf2, gf3, l);
        float tl = PSHFL(tf0, tf1, tf2, tf3, l);
        zv += gl * Wa[l * DD + lane] + tl * Wb[l * DD + lane];
    }
    float ga0 = __shfl(gf0, lane >> 2, 64), ga1 = __shfl(gf1, lane >> 2, 64);
    float ga2 = __shfl(gf2, lane >> 2, 64), ga3 = __shfl(gf3, lane >> 2, 64);
    float ta0 = __shfl(tf0, lane >> 2, 64), ta1 = __shfl(tf1, lane >> 2, 64);
    float ta2 = __shfl(tf2, lane >> 2, 64), ta3 = __shfl(tf3, lane >> 2, 64);
    int j = lane & 3;
    float gfin = j == 0 ? ga0 : j == 1 ? ga1 : j == 2 ? ga2 : ga3;
    float tfin = j == 0 ? ta0 : j == 1 ? ta1 : j == 2 ? ta2 : ta3;
    float gate = 1.0f / (1.0f + __expf(-zv));
    float xn = gate * gfin + (1.0f - gate) * tfin;
    xh_out[oi] = __float2half(xn);
    acc[oi] += xn;
}

// ---------------- host launcher ----------------

extern "C" void kernel_launch(void* const* d_in, const int* in_sizes, int n_in,
                              void* d_out, int out_size, void* d_ws, size_t ws_size,
                              hipStream_t stream) {
    const float* user_emb = (const float*)d_in[0];
    const float* item_emb = (const float*)d_in[1];
    const float* intents  = (const float*)d_in[2];
    const float* W2       = (const float*)d_in[3];
    const float* b2       = (const float*)d_in[4];
    const float* uu_w     = (const float*)d_in[5];
    const float* ii_w     = (const float*)d_in[6];
    const int*   ui_u     = (const int*)d_in[7];
    const int*   ui_i     = (const int*)d_in[8];
    const int*   uu_h     = (const int*)d_in[9];
    const int*   uu_t     = (const int*)d_in[10];
    const int*   ii_h     = (const int*)d_in[11];
    const int*   ii_t     = (const int*)d_in[12];
    float* acc = (float*)d_out;

    char* pw = (char*)d_ws;
    auto allocb = [&](size_t nbytes) -> char* {
        char* r = pw;
        pw += (nbytes + 255) & ~(size_t)255;
        return r;
    };
    // persistent (~266 MB total)
    float* gs    = (float*)allocb((size_t)NN * DD * 4);
    float* ts    = (float*)allocb((size_t)NN * DD * 4);
    float* zp    = (float*)allocb((size_t)NN * DD * 4);
    __half* xh0  = (__half*)allocb((size_t)NN * DD * 2);
    __half* xh1  = (__half*)allocb((size_t)NN * DD * 2);
    __half* c    = (__half*)allocb((size_t)EUI * KK * 2);  // 64 MB; build scratch aliases here
    float* w     = (float*)allocb((size_t)2 * EUI * 4);    // 8 MB (UI both sides)
    float* rs    = (float*)allocb((size_t)NN * 4);
    float* dinv  = (float*)allocb((size_t)NN * 4);
    float* iuu   = (float*)allocb((size_t)NU * 4);
    float* iii   = (float*)allocb((size_t)NI * 4);
    float* Wd_g  = (float*)allocb((size_t)DD * DD * 4);
    float* Wd_t  = (float*)allocb((size_t)DD * DD * 4);
    int* rp_u    = (int*)allocb(((size_t)NU + 1) * 4);
    int* rp_i    = (int*)allocb(((size_t)NI + 1) * 4);
    int* rp_uu   = (int*)allocb(((size_t)NU + 1) * 4);
    int* rp_ii   = (int*)allocb(((size_t)NI + 1) * 4);
    int* rp_ui   = (int*)allocb(((size_t)NN + 1) * 4);
    int* rp_s    = (int*)allocb(((size_t)NN + 1) * 4);
    int* headU   = (int*)allocb((size_t)EUI * 4);
    int* colUI   = (int*)allocb((size_t)2 * EUI * 4);      // 8 MB
    int* head_s  = (int*)allocb((size_t)(EUU + EII) * 4);
    int* col_s   = (int*)allocb((size_t)(EUU + EII) * 4);
    float* bw_s  = (float*)allocb((size_t)(EUU + EII) * 4);
    int* mUI     = (int*)allocb((size_t)EUI * 4);
    float* gwUI  = (float*)allocb((size_t)2 * EUI * 4);    // 8 MB

    // build-time scratch aliased into c
    char* ca = (char*)c;
    int* cur    = (int*)ca;  ca += ((size_t)NU * 4 + 255) & ~(size_t)255;
    int* lst_u  = (int*)ca;  ca += ((size_t)EUI * 4 + 255) & ~(size_t)255;
    int* lst_i  = (int*)ca;  ca += ((size_t)EUI * 4 + 255) & ~(size_t)255;
    int* lst_uu = (int*)ca;  ca += ((size_t)EUU * 4 + 255) & ~(size_t)255;
    int* lst_ii = (int*)ca;  ca += ((size_t)EII * 4 + 255) & ~(size_t)255;
    int* posU   = (int*)ca;

    const int B = 256;

    auto build_csr = [&](const int* h, int E, int n, int* rp, int* lst) {
        hipMemsetAsync(cur, 0, (size_t)n * 4, stream);
        k_count<<<cdiv(E, B), B, 0, stream>>>(h, cur, E);
        k_scan<<<1, 1024, 0, stream>>>(cur, rp, n);
        hipMemsetAsync(cur, 0, (size_t)n * 4, stream);
        k_scatter<<<cdiv(E, B), B, 0, stream>>>(h, rp, cur, lst, E);
    };

    build_csr(ui_u, EUI, NU, rp_u, lst_u);
    build_csr(ui_i, EUI, NI, rp_i, lst_i);
    build_csr(uu_h, EUU, NU, rp_uu, lst_uu);
    build_csr(ii_h, EII, NI, rp_ii, lst_ii);
    k_dinv<<<cdiv(NN, B), B, 0, stream>>>(rp_u, rp_i, dinv);
    k_rowsum_inv<<<cdiv(NU, B), B, 0, stream>>>(rp_uu, lst_uu, uu_w, iuu, NU);
    k_rowsum_inv<<<cdiv(NI, B), B, 0, stream>>>(rp_ii, lst_ii, ii_w, iii, NI);
    k_build_rp2<<<cdiv(NN + 1, B), B, 0, stream>>>(rp_u, rp_i, rp_uu, rp_ii, rp_ui, rp_s);
    k_build_ui<<<cdiv(EUI, B), B, 0, stream>>>(lst_u, ui_u, ui_i, headU, colUI, EUI);
    k_build_colI<<<cdiv(EUI, B), B, 0, stream>>>(lst_i, ui_u, colUI, EUI);
    k_posU<<<cdiv(EUI, B), B, 0, stream>>>(lst_u, posU, EUI);
    k_mapUI<<<cdiv(EUI, B), B, 0, stream>>>(lst_i, posU, mUI, EUI);
    k_build_s<<<cdiv(EUU, B), B, 0, stream>>>(lst_uu, uu_h, uu_t, uu_w, iuu, 0, 0,
                                              head_s, col_s, bw_s, EUU);
    k_build_s<<<cdiv(EII, B), B, 0, stream>>>(lst_ii, ii_h, ii_t, ii_w, iii, NU, EUU,
                                              head_s, col_s, bw_s, EII);
    k_build_gw<<<cdiv(NN, B), B, 0, stream>>>(rp_ui, colUI, dinv, gwUI, NN);
    k_wdiff<<<cdiv(DD * DD, B), B, 0, stream>>>(W2, Wd_g, Wd_t);
    k_init<<<cdiv((long)NN * DD, B), B, 0, stream>>>(user_emb, item_emb, xh0, acc);

    for (int layer = 0; layer < 2; ++layer) {
        const __half* xin = (layer == 0) ? xh0 : xh1;
        __half* xout = (layer == 0) ? xh1 : xh0;

        // ---- UI phase (3 dispatches, whole graph) ----
        k_passA<<<cdiv(EUI, B), B, 0, stream>>>(headU, colUI, xin, intents, c, EUI);
        k_passBC<<<cdiv((long)NN * 8, B), B, 0, stream>>>(rp_ui, mUI, NU, EUI, c, w, rs, NN);
        k_fused_ui<<<cdiv(NN, 8), 512, 0, stream>>>(rp_ui, colUI, gwUI, w, rs,
                                                    Wd_g, Wd_t, b2, xin, gs, ts, zp, NN);

        // ---- UU+II phase (3 dispatches, whole graph) ----
        k_passA<<<cdiv(EUU + EII, B), B, 0, stream>>>(head_s, col_s, xin, intents, c, EUU + EII);
        k_passBC<<<cdiv((long)NN * 8, B), B, 0, stream>>>(rp_s, nullptr, 0, 0, c, w, rs, NN);
        k_fused_fin<<<cdiv(NN, 8), 512, 0, stream>>>(rp_s, col_s, bw_s, w, rs,
                                                     W2 + DD * DD, W2 + 3 * DD * DD,
                                                     xin, gs, ts, zp, xout, acc, NN);
    }
}

// Round 10
// 2247.987 us; speedup vs baseline: 1.4448x; 1.2354x over previous
//
#include <hip/hip_runtime.h>
#include <hip/hip_fp16.h>

#define NU 100000
#define NI 50000
#define NN 150000
#define DD 64
#define KK 32
#define EUI 1000000
#define EUU 500000
#define EII 500000
#define ROWS_PB 64

static inline int cdiv(long a, int b) { return (int)((a + b - 1) / b); }

__device__ __forceinline__ float rdlane(float v, int l) {
    return __int_as_float(__builtin_amdgcn_readlane(__float_as_int(v), l));
}

// ---------------- CSR build ----------------

__global__ void k_count(const int* __restrict__ h, int* __restrict__ cnt, int E) {
    int e = blockIdx.x * blockDim.x + threadIdx.x;
    if (e < E) atomicAdd(&cnt[h[e]], 1);
}

__global__ __launch_bounds__(1024) void k_scan(const int* __restrict__ cnt,
                                               int* __restrict__ rp, int n) {
    __shared__ int wsum[16];
    __shared__ int carry_s;
    int tid = threadIdx.x;
    int lane = tid & 63, wid = tid >> 6;
    if (tid == 0) carry_s = 0;
    __syncthreads();
    for (int base = 0; base < n; base += 1024) {
        int i = base + tid;
        int v = (i < n) ? cnt[i] : 0;
        int s = v;
#pragma unroll
        for (int off = 1; off < 64; off <<= 1) {
            int t = __shfl_up(s, off, 64);
            if (lane >= off) s += t;
        }
        if (lane == 63) wsum[wid] = s;
        __syncthreads();
        int woff = 0, total = 0;
#pragma unroll
        for (int w = 0; w < 16; w++) { int ws = wsum[w]; total += ws; if (w < wid) woff += ws; }
        int carry = carry_s;
        if (i < n) rp[i] = carry + woff + (s - v);
        __syncthreads();
        if (tid == 0) carry_s = carry + total;
        __syncthreads();
    }
    if (tid == 0) rp[n] = carry_s;
}

__global__ void k_scatter(const int* __restrict__ h, const int* __restrict__ rp,
                          int* __restrict__ cur, int* __restrict__ lst, int E) {
    int e = blockIdx.x * blockDim.x + threadIdx.x;
    if (e >= E) return;
    int r = h[e];
    int p = rp[r] + atomicAdd(&cur[r], 1);
    lst[p] = e;
}

__global__ void k_dinv(const int* __restrict__ rpu, const int* __restrict__ rpi,
                       float* __restrict__ dinv) {
    int t = blockIdx.x * blockDim.x + threadIdx.x;
    if (t >= NN) return;
    int deg = (t < NU) ? rpu[t + 1] - rpu[t] : rpi[t - NU + 1] - rpi[t - NU];
    dinv[t] = deg > 0 ? rsqrtf((float)deg) : 0.0f;
}

__global__ void k_rowsum_inv(const int* __restrict__ rp, const int* __restrict__ lst,
                             const float* __restrict__ w, float* __restrict__ out, int n) {
    int r = blockIdx.x * blockDim.x + threadIdx.x;
    if (r >= n) return;
    float s = 0.f;
    int e1 = rp[r + 1];
    for (int e = rp[r]; e < e1; e++) s += w[lst[e]];
    out[r] = (s != 0.0f) ? 1.0f / s : 0.0f;
}

__global__ void k_wdiff(const float* __restrict__ W2, float* __restrict__ Wd_g,
                        float* __restrict__ Wd_t) {
    int i = blockIdx.x * blockDim.x + threadIdx.x;
    if (i >= DD * DD) return;
    Wd_g[i] = W2[i] - W2[DD * DD + i];
    Wd_t[i] = W2[2 * DD * DD + i] - W2[3 * DD * DD + i];
}

__global__ void k_init(const float* __restrict__ ue, const float* __restrict__ ie,
                       __half* __restrict__ xh, float* __restrict__ acc) {
    size_t i = (size_t)blockIdx.x * blockDim.x + threadIdx.x;
    if (i >= (size_t)NN * DD) return;
    float v = (i < (size_t)NU * DD) ? ue[i] : ie[i - (size_t)NU * DD];
    xh[i] = __float2half(v);
    acc[i] = v;
}

// ---------------- map-building kernels (x-independent, run once) ----------------

__global__ void k_posU(const int* __restrict__ lst, int* __restrict__ pos, int E) {
    int p = blockIdx.x * blockDim.x + threadIdx.x;
    if (p < E) pos[lst[p]] = p;
}

__global__ void k_mapUI(const int* __restrict__ lst_i, const int* __restrict__ posU,
                        int* __restrict__ mUI, int E) {
    int p = blockIdx.x * blockDim.x + threadIdx.x;
    if (p < E) mUI[p] = posU[lst_i[p]];
}

__global__ void k_build_ui(const int* __restrict__ lst_u, const int* __restrict__ ui_u,
                           const int* __restrict__ ui_i, int* __restrict__ headU,
                           int* __restrict__ colUI, int E) {
    int p = blockIdx.x * blockDim.x + threadIdx.x;
    if (p >= E) return;
    int e = lst_u[p];
    headU[p] = ui_u[e];
    colUI[p] = ui_i[e] + NU;
}

__global__ void k_build_colI(const int* __restrict__ lst_i, const int* __restrict__ ui_u,
                             int* __restrict__ colUI, int E) {
    int p = blockIdx.x * blockDim.x + threadIdx.x;
    if (p < E) colUI[EUI + p] = ui_u[lst_i[p]];
}

__global__ void k_build_rp2(const int* __restrict__ rp_u, const int* __restrict__ rp_i,
                            const int* __restrict__ rp_uu, const int* __restrict__ rp_ii,
                            int* __restrict__ rp_ui, int* __restrict__ rp_s) {
    int t = blockIdx.x * blockDim.x + threadIdx.x;
    if (t > NN) return;
    rp_ui[t] = (t <= NU) ? rp_u[t] : rp_i[t - NU] + EUI;
    rp_s[t]  = (t <= NU) ? rp_uu[t] : rp_ii[t - NU] + EUU;
}

__global__ void k_build_gw(const int* __restrict__ rp, const int* __restrict__ col,
                           const float* __restrict__ dinv, float* __restrict__ gw, int n) {
    int r = blockIdx.x * blockDim.x + threadIdx.x;
    if (r >= n) return;
    float dh = dinv[r];
    int e1 = rp[r + 1];
    for (int p = rp[r]; p < e1; p++) gw[p] = dh * dinv[col[p]];
}

__global__ void k_build_s(const int* __restrict__ lst, const int* __restrict__ eh,
                          const int* __restrict__ et, const float* __restrict__ ew,
                          const float* __restrict__ inv, int off, int peo,
                          int* __restrict__ head, int* __restrict__ col,
                          float* __restrict__ bw, int E) {
    int p = blockIdx.x * blockDim.x + threadIdx.x;
    if (p >= E) return;
    int e = lst[p];
    int h = eh[e];
    head[peo + p] = h + off;
    col[peo + p] = et[e] + off;
    bw[peo + p] = ew[e] * inv[h];
}

// ---------------- pass A (CSR order, grid-stride): c[p] = alpha * dist, fp16 -----------

__global__ __launch_bounds__(256) void k_passA(
        const int* __restrict__ head, const int* __restrict__ col,
        const __half* __restrict__ x, const float* __restrict__ intents,
        __half* __restrict__ c_out, int E) {
    __shared__ float Wl[DD * KK];
    for (int idx = threadIdx.x; idx < DD * KK; idx += blockDim.x) Wl[idx] = intents[idx];
    __syncthreads();
    int stride = gridDim.x * blockDim.x;
    for (int p = blockIdx.x * blockDim.x + threadIdx.x; p < E; p += stride) {
        const uint4* hp = (const uint4*)(x + (size_t)head[p] * DD);
        const uint4* tp = (const uint4*)(x + (size_t)col[p] * DD);
        uint4 hraw[8], traw[8];
#pragma unroll
        for (int j = 0; j < 8; j++) hraw[j] = hp[j];
#pragma unroll
        for (int j = 0; j < 8; j++) traw[j] = tp[j];
        const __half2* h2 = (const __half2*)hraw;
        const __half2* t2 = (const __half2*)traw;
        float logit[KK];
#pragma unroll
        for (int k = 0; k < KK; k++) logit[k] = 0.f;
        float dot = 0.f;
#pragma unroll 4
        for (int l4 = 0; l4 < 16; l4++) {
            float2 ha = __half22float2(h2[2 * l4]), hb = __half22float2(h2[2 * l4 + 1]);
            float2 ta = __half22float2(t2[2 * l4]), tb = __half22float2(t2[2 * l4 + 1]);
            float p0 = ha.x * ta.x, p1 = ha.y * ta.y, p2 = hb.x * tb.x, p3 = hb.y * tb.y;
            dot += p0 + p1 + p2 + p3;
            const float* w = &Wl[l4 * 4 * KK];
#pragma unroll
            for (int k = 0; k < KK; k++)
                logit[k] += p0 * w[k] + p1 * w[KK + k] + p2 * w[2 * KK + k] + p3 * w[3 * KK + k];
        }
        float m = logit[0];
#pragma unroll
        for (int k = 1; k < KK; k++) m = fmaxf(m, logit[k]);
        float ssum = 0.f;
#pragma unroll
        for (int k = 0; k < KK; k++) { float ev = __expf(logit[k] - m); logit[k] = ev; ssum += ev; }
        float scale = 0.5f * (dot + 1.0f) / ssum;
        uint4 pk[4];
        unsigned int* u = (unsigned int*)pk;
#pragma unroll
        for (int k2 = 0; k2 < 16; k2++) {
            __half2 hh = __floats2half2_rn(logit[2 * k2] * scale, logit[2 * k2 + 1] * scale);
            u[k2] = *reinterpret_cast<const unsigned int*>(&hh);
        }
        uint4* dst = (uint4*)(c_out + (size_t)p * KK);
#pragma unroll
        for (int q = 0; q < 4; q++) dst[q] = pk[q];
    }
}

// ---------------- pass B+C over all NN nodes ----------------
__global__ __launch_bounds__(256) void k_passBC(const int* __restrict__ rp,
                                                const int* __restrict__ map,
                                                int nsplit, int peoff,
                                                const __half* __restrict__ c,
                                                float* __restrict__ w,
                                                float* __restrict__ rsinv, int n) {
    int gid = blockIdx.x * blockDim.x + threadIdx.x;
    int node = gid >> 3, j = gid & 7;
    if (node >= n) return;
    bool use_map = (map != nullptr) && (node >= nsplit);
    int p0 = rp[node], p1 = rp[node + 1];
    const uint2* cp = (const uint2*)c;
    float4 agg = make_float4(0.f, 0.f, 0.f, 0.f);
    for (int p = p0; p < p1; p++) {
        int idx = use_map ? map[p - peoff] : p;
        uint2 v = cp[(size_t)idx * 8 + j];
        float2 fa = __half22float2(*reinterpret_cast<const __half2*>(&v.x));
        float2 fb = __half22float2(*reinterpret_cast<const __half2*>(&v.y));
        agg.x += fa.x; agg.y += fa.y; agg.z += fb.x; agg.w += fb.y;
    }
    float4 rec;
    rec.x = (agg.x != 0.f) ? 1.f / agg.x : 0.f;
    rec.y = (agg.y != 0.f) ? 1.f / agg.y : 0.f;
    rec.z = (agg.z != 0.f) ? 1.f / agg.z : 0.f;
    rec.w = (agg.w != 0.f) ? 1.f / agg.w : 0.f;
    float rs = 0.f;
    for (int p = p0; p < p1; p++) {
        int idx = use_map ? map[p - peoff] : p;
        uint2 v = cp[(size_t)idx * 8 + j];
        float2 fa = __half22float2(*reinterpret_cast<const __half2*>(&v.x));
        float2 fb = __half22float2(*reinterpret_cast<const __half2*>(&v.y));
        float dot = fa.x * rec.x + fa.y * rec.y + fb.x * rec.z + fb.y * rec.w;
        dot += __shfl_xor(dot, 1, 64);
        dot += __shfl_xor(dot, 2, 64);
        dot += __shfl_xor(dot, 4, 64);
        float wv = dot * (1.0f / KK);
        if (j == 0) w[p] = wv;
        rs += wv;
    }
    if (j == 0) rsinv[node] = (rs != 0.f) ? 1.f / rs : 0.f;
}

// readlane-based broadcast of packed component (l compile-time)
#define PRD(a0, a1, a2, a3, l) \
    rdlane(((l) & 3) == 0 ? (a0) : ((l) & 3) == 1 ? (a1) : ((l) & 3) == 2 ? (a2) : (a3), (l) >> 2)

// ---------------- fused UI over NN rows: g1 + t1 + z-preact; 64 rows/block ----------------
__global__ __launch_bounds__(512) void k_fused_ui(
        const int* __restrict__ rp, const int* __restrict__ col,
        const float* __restrict__ gw, const float* __restrict__ w,
        const float* __restrict__ rsinv, const float* __restrict__ Wd_g,
        const float* __restrict__ Wd_t, const float* __restrict__ b2,
        const __half* __restrict__ x, float* __restrict__ gs, float* __restrict__ ts,
        float* __restrict__ zp, int nrows) {
    __shared__ float Wg[DD * DD];
    __shared__ float Wt[DD * DD];
    for (int i = threadIdx.x; i < DD * DD; i += 512) { Wg[i] = Wd_g[i]; Wt[i] = Wd_t[i]; }
    __syncthreads();
    int wid = threadIdx.x >> 6, lane = threadIdx.x & 63;
    int sub = lane & 15, grp = lane >> 4;
    float b2v = b2[lane];
    const uint2* xq = (const uint2*)x;
    int rbase = blockIdx.x * ROWS_PB + wid * 8;
    for (int rr = 0; rr < 8; rr++) {
        int r = rbase + rr;
        if (r >= nrows) break;
        float g0 = 0, g1 = 0, g2 = 0, g3 = 0, t0 = 0, t1 = 0, t2 = 0, t3 = 0;
        int e = rp[r], e1 = rp[r + 1];
        for (; e + 8 <= e1; e += 8) {
#pragma unroll
            for (int u = 0; u < 2; u++) {
                int idx = e + 4 * u + grp;
                int cc = col[idx];
                float wg = gw[idx], wt = w[idx];
                uint2 raw = xq[(size_t)cc * 16 + sub];
                float2 xa = __half22float2(*(const __half2*)&raw.x);
                float2 xb = __half22float2(*(const __half2*)&raw.y);
                g0 += wg * xa.x; g1 += wg * xa.y; g2 += wg * xb.x; g3 += wg * xb.y;
                t0 += wt * xa.x; t1 += wt * xa.y; t2 += wt * xb.x; t3 += wt * xb.y;
            }
        }
        for (; e < e1; e += 4) {
            int idx = e + grp;
            if (idx < e1) {
                int cc = col[idx];
                float wg = gw[idx], wt = w[idx];
                uint2 raw = xq[(size_t)cc * 16 + sub];
                float2 xa = __half22float2(*(const __half2*)&raw.x);
                float2 xb = __half22float2(*(const __half2*)&raw.y);
                g0 += wg * xa.x; g1 += wg * xa.y; g2 += wg * xb.x; g3 += wg * xb.y;
                t0 += wt * xa.x; t1 += wt * xa.y; t2 += wt * xb.x; t3 += wt * xb.y;
            }
        }
#pragma unroll
        for (int off = 16; off <= 32; off <<= 1) {
            g0 += __shfl_xor(g0, off, 64); g1 += __shfl_xor(g1, off, 64);
            g2 += __shfl_xor(g2, off, 64); g3 += __shfl_xor(g3, off, 64);
            t0 += __shfl_xor(t0, off, 64); t1 += __shfl_xor(t1, off, 64);
            t2 += __shfl_xor(t2, off, 64); t3 += __shfl_xor(t3, off, 64);
        }
        float rsv = rsinv[r];
        t0 *= rsv; t1 *= rsv; t2 *= rsv; t3 *= rsv;
        float ss = t0 * t0 + t1 * t1 + t2 * t2 + t3 * t3;
        ss += __shfl_xor(ss, 1, 64); ss += __shfl_xor(ss, 2, 64);
        ss += __shfl_xor(ss, 4, 64); ss += __shfl_xor(ss, 8, 64);
        float inv_n = 1.0f / fmaxf(sqrtf(ss), 1e-12f);
        t0 *= inv_n; t1 *= inv_n; t2 *= inv_n; t3 *= inv_n;
        float zv = b2v;
#pragma unroll
        for (int l = 0; l < DD; l++) {
            float gl = PRD(g0, g1, g2, g3, l);
            float tl = PRD(t0, t1, t2, t3, l);
            zv += gl * Wg[l * DD + lane] + tl * Wt[l * DD + lane];
        }
        float ga0 = __shfl(g0, lane >> 2, 64), ga1 = __shfl(g1, lane >> 2, 64);
        float ga2 = __shfl(g2, lane >> 2, 64), ga3 = __shfl(g3, lane >> 2, 64);
        float ta0 = __shfl(t0, lane >> 2, 64), ta1 = __shfl(t1, lane >> 2, 64);
        float ta2 = __shfl(t2, lane >> 2, 64), ta3 = __shfl(t3, lane >> 2, 64);
        int j = lane & 3;
        float gsv = j == 0 ? ga0 : j == 1 ? ga1 : j == 2 ? ga2 : ga3;
        float tsv = j == 0 ? ta0 : j == 1 ? ta1 : j == 2 ? ta2 : ta3;
        size_t oi = (size_t)r * DD + lane;
        gs[oi] = gsv;
        ts[oi] = tsv;
        zp[oi] = zv;
    }
}

// ---------------- fused finalize over NN rows: g2 + t2 + gate + combine; 64 rows/block ---
__global__ __launch_bounds__(512) void k_fused_fin(
        const int* __restrict__ rp, const int* __restrict__ col,
        const float* __restrict__ bw, const float* __restrict__ w,
        const float* __restrict__ rsinv,
        const float* __restrict__ W1, const float* __restrict__ W3,
        const __half* __restrict__ x, const float* __restrict__ gs,
        const float* __restrict__ ts, const float* __restrict__ zp,
        __half* __restrict__ xh_out, float* __restrict__ acc, int nrows) {
    __shared__ float Wa[DD * DD];
    __shared__ float Wb[DD * DD];
    for (int i = threadIdx.x; i < DD * DD; i += 512) { Wa[i] = W1[i]; Wb[i] = W3[i]; }
    __syncthreads();
    int wid = threadIdx.x >> 6, lane = threadIdx.x & 63;
    int sub = lane & 15, grp = lane >> 4;
    const uint2* xq = (const uint2*)x;
    int rbase = blockIdx.x * ROWS_PB + wid * 8;
    for (int rr = 0; rr < 8; rr++) {
        int r = rbase + rr;
        if (r >= nrows) break;
        float g0 = 0, g1 = 0, g2 = 0, g3 = 0, t0 = 0, t1 = 0, t2 = 0, t3 = 0;
        int e = rp[r], e1 = rp[r + 1];
        for (; e + 8 <= e1; e += 8) {
#pragma unroll
            for (int u = 0; u < 2; u++) {
                int idx = e + 4 * u + grp;
                int cc = col[idx];
                float wg = bw[idx], wt = w[idx];
                uint2 raw = xq[(size_t)cc * 16 + sub];
                float2 xa = __half22float2(*(const __half2*)&raw.x);
                float2 xb = __half22float2(*(const __half2*)&raw.y);
                g0 += wg * xa.x; g1 += wg * xa.y; g2 += wg * xb.x; g3 += wg * xb.y;
                t0 += wt * xa.x; t1 += wt * xa.y; t2 += wt * xb.x; t3 += wt * xb.y;
            }
        }
        for (; e < e1; e += 4) {
            int idx = e + grp;
            if (idx < e1) {
                int cc = col[idx];
                float wg = bw[idx], wt = w[idx];
                uint2 raw = xq[(size_t)cc * 16 + sub];
                float2 xa = __half22float2(*(const __half2*)&raw.x);
                float2 xb = __half22float2(*(const __half2*)&raw.y);
                g0 += wg * xa.x; g1 += wg * xa.y; g2 += wg * xb.x; g3 += wg * xb.y;
                t0 += wt * xa.x; t1 += wt * xa.y; t2 += wt * xb.x; t3 += wt * xb.y;
            }
        }
#pragma unroll
        for (int off = 16; off <= 32; off <<= 1) {
            g0 += __shfl_xor(g0, off, 64); g1 += __shfl_xor(g1, off, 64);
            g2 += __shfl_xor(g2, off, 64); g3 += __shfl_xor(g3, off, 64);
            t0 += __shfl_xor(t0, off, 64); t1 += __shfl_xor(t1, off, 64);
            t2 += __shfl_xor(t2, off, 64); t3 += __shfl_xor(t3, off, 64);
        }
        float rsv = rsinv[r];
        t0 *= rsv; t1 *= rsv; t2 *= rsv; t3 *= rsv;
        float ss = t0 * t0 + t1 * t1 + t2 * t2 + t3 * t3;
        ss += __shfl_xor(ss, 1, 64); ss += __shfl_xor(ss, 2, 64);
        ss += __shfl_xor(ss, 4, 64); ss += __shfl_xor(ss, 8, 64);
        float inv_n = 1.0f / fmaxf(sqrtf(ss), 1e-12f);
        t0 *= inv_n; t1 *= inv_n; t2 *= inv_n; t3 *= inv_n;
        float4 gp = ((const float4*)(gs + (size_t)r * DD))[sub];
        float4 tp = ((const float4*)(ts + (size_t)r * DD))[sub];
        float gf0 = gp.x + g0, gf1 = gp.y + g1, gf2 = gp.z + g2, gf3 = gp.w + g3;
        float tf0 = tp.x + t0, tf1 = tp.y + t1, tf2 = tp.z + t2, tf3 = tp.w + t3;
        size_t oi = (size_t)r * DD + lane;
        float zv = zp[oi];
#pragma unroll
        for (int l = 0; l < DD; l++) {
            float gl = PRD(gf0, gf1, gf2, gf3, l);
            float tl = PRD(tf0, tf1, tf2, tf3, l);
            zv += gl * Wa[l * DD + lane] + tl * Wb[l * DD + lane];
        }
        float ga0 = __shfl(gf0, lane >> 2, 64), ga1 = __shfl(gf1, lane >> 2, 64);
        float ga2 = __shfl(gf2, lane >> 2, 64), ga3 = __shfl(gf3, lane >> 2, 64);
        float ta0 = __shfl(tf0, lane >> 2, 64), ta1 = __shfl(tf1, lane >> 2, 64);
        float ta2 = __shfl(tf2, lane >> 2, 64), ta3 = __shfl(tf3, lane >> 2, 64);
        int j = lane & 3;
        float gfin = j == 0 ? ga0 : j == 1 ? ga1 : j == 2 ? ga2 : ga3;
        float tfin = j == 0 ? ta0 : j == 1 ? ta1 : j == 2 ? ta2 : ta3;
        float gate = 1.0f / (1.0f + __expf(-zv));
        float xn = gate * gfin + (1.0f - gate) * tfin;
        xh_out[oi] = __float2half(xn);
        acc[oi] += xn;
    }
}

// ---------------- host launcher ----------------

extern "C" void kernel_launch(void* const* d_in, const int* in_sizes, int n_in,
                              void* d_out, int out_size, void* d_ws, size_t ws_size,
                              hipStream_t stream) {
    const float* user_emb = (const float*)d_in[0];
    const float* item_emb = (const float*)d_in[1];
    const float* intents  = (const float*)d_in[2];
    const float* W2       = (const float*)d_in[3];
    const float* b2       = (const float*)d_in[4];
    const float* uu_w     = (const float*)d_in[5];
    const float* ii_w     = (const float*)d_in[6];
    const int*   ui_u     = (const int*)d_in[7];
    const int*   ui_i     = (const int*)d_in[8];
    const int*   uu_h     = (const int*)d_in[9];
    const int*   uu_t     = (const int*)d_in[10];
    const int*   ii_h     = (const int*)d_in[11];
    const int*   ii_t     = (const int*)d_in[12];
    float* acc = (float*)d_out;

    char* pw = (char*)d_ws;
    auto allocb = [&](size_t nbytes) -> char* {
        char* r = pw;
        pw += (nbytes + 255) & ~(size_t)255;
        return r;
    };
    float* gs    = (float*)allocb((size_t)NN * DD * 4);
    float* ts    = (float*)allocb((size_t)NN * DD * 4);
    float* zp    = (float*)allocb((size_t)NN * DD * 4);
    __half* xh0  = (__half*)allocb((size_t)NN * DD * 2);
    __half* xh1  = (__half*)allocb((size_t)NN * DD * 2);
    __half* c    = (__half*)allocb((size_t)EUI * KK * 2);  // 64 MB; build scratch aliases here
    float* w     = (float*)allocb((size_t)2 * EUI * 4);
    float* rs    = (float*)allocb((size_t)NN * 4);
    float* dinv  = (float*)allocb((size_t)NN * 4);
    float* iuu   = (float*)allocb((size_t)NU * 4);
    float* iii   = (float*)allocb((size_t)NI * 4);
    float* Wd_g  = (float*)allocb((size_t)DD * DD * 4);
    float* Wd_t  = (float*)allocb((size_t)DD * DD * 4);
    int* rp_u    = (int*)allocb(((size_t)NU + 1) * 4);
    int* rp_i    = (int*)allocb(((size_t)NI + 1) * 4);
    int* rp_uu   = (int*)allocb(((size_t)NU + 1) * 4);
    int* rp_ii   = (int*)allocb(((size_t)NI + 1) * 4);
    int* rp_ui   = (int*)allocb(((size_t)NN + 1) * 4);
    int* rp_s    = (int*)allocb(((size_t)NN + 1) * 4);
    int* headU   = (int*)allocb((size_t)EUI * 4);
    int* colUI   = (int*)allocb((size_t)2 * EUI * 4);
    int* head_s  = (int*)allocb((size_t)(EUU + EII) * 4);
    int* col_s   = (int*)allocb((size_t)(EUU + EII) * 4);
    float* bw_s  = (float*)allocb((size_t)(EUU + EII) * 4);
    int* mUI     = (int*)allocb((size_t)EUI * 4);
    float* gwUI  = (float*)allocb((size_t)2 * EUI * 4);

    char* ca = (char*)c;
    int* cur    = (int*)ca;  ca += ((size_t)NU * 4 + 255) & ~(size_t)255;
    int* lst_u  = (int*)ca;  ca += ((size_t)EUI * 4 + 255) & ~(size_t)255;
    int* lst_i  = (int*)ca;  ca += ((size_t)EUI * 4 + 255) & ~(size_t)255;
    int* lst_uu = (int*)ca;  ca += ((size_t)EUU * 4 + 255) & ~(size_t)255;
    int* lst_ii = (int*)ca;  ca += ((size_t)EII * 4 + 255) & ~(size_t)255;
    int* posU   = (int*)ca;

    const int B = 256;

    auto build_csr = [&](const int* h, int E, int n, int* rp, int* lst) {
        hipMemsetAsync(cur, 0, (size_t)n * 4, stream);
        k_count<<<cdiv(E, B), B, 0, stream>>>(h, cur, E);
        k_scan<<<1, 1024, 0, stream>>>(cur, rp, n);
        hipMemsetAsync(cur, 0, (size_t)n * 4, stream);
        k_scatter<<<cdiv(E, B), B, 0, stream>>>(h, rp, cur, lst, E);
    };

    build_csr(ui_u, EUI, NU, rp_u, lst_u);
    build_csr(ui_i, EUI, NI, rp_i, lst_i);
    build_csr(uu_h, EUU, NU, rp_uu, lst_uu);
    build_csr(ii_h, EII, NI, rp_ii, lst_ii);
    k_dinv<<<cdiv(NN, B), B, 0, stream>>>(rp_u, rp_i, dinv);
    k_rowsum_inv<<<cdiv(NU, B), B, 0, stream>>>(rp_uu, lst_uu, uu_w, iuu, NU);
    k_rowsum_inv<<<cdiv(NI, B), B, 0, stream>>>(rp_ii, lst_ii, ii_w, iii, NI);
    k_build_rp2<<<cdiv(NN + 1, B), B, 0, stream>>>(rp_u, rp_i, rp_uu, rp_ii, rp_ui, rp_s);
    k_build_ui<<<cdiv(EUI, B), B, 0, stream>>>(lst_u, ui_u, ui_i, headU, colUI, EUI);
    k_build_colI<<<cdiv(EUI, B), B, 0, stream>>>(lst_i, ui_u, colUI, EUI);
    k_posU<<<cdiv(EUI, B), B, 0, stream>>>(lst_u, posU, EUI);
    k_mapUI<<<cdiv(EUI, B), B, 0, stream>>>(lst_i, posU, mUI, EUI);
    k_build_s<<<cdiv(EUU, B), B, 0, stream>>>(lst_uu, uu_h, uu_t, uu_w, iuu, 0, 0,
                                              head_s, col_s, bw_s, EUU);
    k_build_s<<<cdiv(EII, B), B, 0, stream>>>(lst_ii, ii_h, ii_t, ii_w, iii, NU, EUU,
                                              head_s, col_s, bw_s, EII);
    k_build_gw<<<cdiv(NN, B), B, 0, stream>>>(rp_ui, colUI, dinv, gwUI, NN);
    k_wdiff<<<cdiv(DD * DD, B), B, 0, stream>>>(W2, Wd_g, Wd_t);
    k_init<<<cdiv((long)NN * DD, B), B, 0, stream>>>(user_emb, item_emb, xh0, acc);

    for (int layer = 0; layer < 2; ++layer) {
        const __half* xin = (layer == 0) ? xh0 : xh1;
        __half* xout = (layer == 0) ? xh1 : xh0;

        // ---- UI phase ----
        k_passA<<<1024, B, 0, stream>>>(headU, colUI, xin, intents, c, EUI);
        k_passBC<<<cdiv((long)NN * 8, B), B, 0, stream>>>(rp_ui, mUI, NU, EUI, c, w, rs, NN);
        k_fused_ui<<<cdiv(NN, ROWS_PB), 512, 0, stream>>>(rp_ui, colUI, gwUI, w, rs,
                                                          Wd_g, Wd_t, b2, xin, gs, ts, zp, NN);

        // ---- UU+II phase ----
        k_passA<<<1024, B, 0, stream>>>(head_s, col_s, xin, intents, c, EUU + EII);
        k_passBC<<<cdiv((long)NN * 8, B), B, 0, stream>>>(rp_s, nullptr, 0, 0, c, w, rs, NN);
        k_fused_fin<<<cdiv(NN, ROWS_PB), 512, 0, stream>>>(rp_s, col_s, bw_s, w, rs,
                                                           W2 + DD * DD, W2 + 3 * DD * DD,
                                                           xin, gs, ts, zp, xout, acc, NN);
    }
}

// Round 11
// 2234.070 us; speedup vs baseline: 1.4538x; 1.0062x over previous
//
#include <hip/hip_runtime.h>
#include <hip/hip_fp16.h>

#define NU 100000
#define NI 50000
#define NN 150000
#define DD 64
#define KK 32
#define EUI 1000000
#define EUU 500000
#define EII 500000
#define ROWS_PB 64

static inline int cdiv(long a, int b) { return (int)((a + b - 1) / b); }

__device__ __forceinline__ float rdlane(float v, int l) {
    return __int_as_float(__builtin_amdgcn_readlane(__float_as_int(v), l));
}

// ---------------- CSR build ----------------

__global__ void k_count(const int* __restrict__ h, int* __restrict__ cnt, int E) {
    int e = blockIdx.x * blockDim.x + threadIdx.x;
    if (e < E) atomicAdd(&cnt[h[e]], 1);
}

__global__ __launch_bounds__(1024) void k_scan(const int* __restrict__ cnt,
                                               int* __restrict__ rp, int n) {
    __shared__ int wsum[16];
    __shared__ int carry_s;
    int tid = threadIdx.x;
    int lane = tid & 63, wid = tid >> 6;
    if (tid == 0) carry_s = 0;
    __syncthreads();
    for (int base = 0; base < n; base += 1024) {
        int i = base + tid;
        int v = (i < n) ? cnt[i] : 0;
        int s = v;
#pragma unroll
        for (int off = 1; off < 64; off <<= 1) {
            int t = __shfl_up(s, off, 64);
            if (lane >= off) s += t;
        }
        if (lane == 63) wsum[wid] = s;
        __syncthreads();
        int woff = 0, total = 0;
#pragma unroll
        for (int w = 0; w < 16; w++) { int ws = wsum[w]; total += ws; if (w < wid) woff += ws; }
        int carry = carry_s;
        if (i < n) rp[i] = carry + woff + (s - v);
        __syncthreads();
        if (tid == 0) carry_s = carry + total;
        __syncthreads();
    }
    if (tid == 0) rp[n] = carry_s;
}

__global__ void k_scatter(const int* __restrict__ h, const int* __restrict__ rp,
                          int* __restrict__ cur, int* __restrict__ lst, int E) {
    int e = blockIdx.x * blockDim.x + threadIdx.x;
    if (e >= E) return;
    int r = h[e];
    int p = rp[r] + atomicAdd(&cur[r], 1);
    lst[p] = e;
}

__global__ void k_dinv(const int* __restrict__ rpu, const int* __restrict__ rpi,
                       float* __restrict__ dinv) {
    int t = blockIdx.x * blockDim.x + threadIdx.x;
    if (t >= NN) return;
    int deg = (t < NU) ? rpu[t + 1] - rpu[t] : rpi[t - NU + 1] - rpi[t - NU];
    dinv[t] = deg > 0 ? rsqrtf((float)deg) : 0.0f;
}

__global__ void k_rowsum_inv(const int* __restrict__ rp, const int* __restrict__ lst,
                             const float* __restrict__ w, float* __restrict__ out, int n) {
    int r = blockIdx.x * blockDim.x + threadIdx.x;
    if (r >= n) return;
    float s = 0.f;
    int e1 = rp[r + 1];
    for (int e = rp[r]; e < e1; e++) s += w[lst[e]];
    out[r] = (s != 0.0f) ? 1.0f / s : 0.0f;
}

__global__ void k_wdiff(const float* __restrict__ W2, float* __restrict__ Wd_g,
                        float* __restrict__ Wd_t) {
    int i = blockIdx.x * blockDim.x + threadIdx.x;
    if (i >= DD * DD) return;
    Wd_g[i] = W2[i] - W2[DD * DD + i];
    Wd_t[i] = W2[2 * DD * DD + i] - W2[3 * DD * DD + i];
}

__global__ void k_init(const float* __restrict__ ue, const float* __restrict__ ie,
                       __half* __restrict__ xh, float* __restrict__ acc) {
    size_t i = (size_t)blockIdx.x * blockDim.x + threadIdx.x;
    if (i >= (size_t)NN * DD) return;
    float v = (i < (size_t)NU * DD) ? ue[i] : ie[i - (size_t)NU * DD];
    xh[i] = __float2half(v);
    acc[i] = v;
}

// ---------------- map-building kernels (x-independent, run once) ----------------

__global__ void k_posU(const int* __restrict__ lst, int* __restrict__ pos, int E) {
    int p = blockIdx.x * blockDim.x + threadIdx.x;
    if (p < E) pos[lst[p]] = p;
}

__global__ void k_mapUI(const int* __restrict__ lst_i, const int* __restrict__ posU,
                        int* __restrict__ mUI, int E) {
    int p = blockIdx.x * blockDim.x + threadIdx.x;
    if (p < E) mUI[p] = posU[lst_i[p]];
}

__global__ void k_build_ui(const int* __restrict__ lst_u, const int* __restrict__ ui_u,
                           const int* __restrict__ ui_i, int* __restrict__ headU,
                           int* __restrict__ colUI, int E) {
    int p = blockIdx.x * blockDim.x + threadIdx.x;
    if (p >= E) return;
    int e = lst_u[p];
    headU[p] = ui_u[e];
    colUI[p] = ui_i[e] + NU;
}

__global__ void k_build_colI(const int* __restrict__ lst_i, const int* __restrict__ ui_u,
                             int* __restrict__ colUI, int E) {
    int p = blockIdx.x * blockDim.x + threadIdx.x;
    if (p < E) colUI[EUI + p] = ui_u[lst_i[p]];
}

__global__ void k_build_rp2(const int* __restrict__ rp_u, const int* __restrict__ rp_i,
                            const int* __restrict__ rp_uu, const int* __restrict__ rp_ii,
                            int* __restrict__ rp_ui, int* __restrict__ rp_s) {
    int t = blockIdx.x * blockDim.x + threadIdx.x;
    if (t > NN) return;
    rp_ui[t] = (t <= NU) ? rp_u[t] : rp_i[t - NU] + EUI;
    rp_s[t]  = (t <= NU) ? rp_uu[t] : rp_ii[t - NU] + EUU;
}

__global__ void k_build_gw(const int* __restrict__ rp, const int* __restrict__ col,
                           const float* __restrict__ dinv, float* __restrict__ gw, int n) {
    int r = blockIdx.x * blockDim.x + threadIdx.x;
    if (r >= n) return;
    float dh = dinv[r];
    int e1 = rp[r + 1];
    for (int p = rp[r]; p < e1; p++) gw[p] = dh * dinv[col[p]];
}

__global__ void k_build_s(const int* __restrict__ lst, const int* __restrict__ eh,
                          const int* __restrict__ et, const float* __restrict__ ew,
                          const float* __restrict__ inv, int off, int peo,
                          int* __restrict__ head, int* __restrict__ col,
                          float* __restrict__ bw, int E) {
    int p = blockIdx.x * blockDim.x + threadIdx.x;
    if (p >= E) return;
    int e = lst[p];
    int h = eh[e];
    head[peo + p] = h + off;
    col[peo + p] = et[e] + off;
    bw[peo + p] = ew[e] * inv[h];
}

// ---------------- pass A (CSR order, grid-stride): c[p] = alpha * dist, fp16 -----------

__global__ __launch_bounds__(256) void k_passA(
        const int* __restrict__ head, const int* __restrict__ col,
        const __half* __restrict__ x, const float* __restrict__ intents,
        __half* __restrict__ c_out, int E) {
    __shared__ float Wl[DD * KK];
    for (int idx = threadIdx.x; idx < DD * KK; idx += blockDim.x) Wl[idx] = intents[idx];
    __syncthreads();
    int stride = gridDim.x * blockDim.x;
    for (int p = blockIdx.x * blockDim.x + threadIdx.x; p < E; p += stride) {
        const uint4* hp = (const uint4*)(x + (size_t)head[p] * DD);
        const uint4* tp = (const uint4*)(x + (size_t)col[p] * DD);
        uint4 hraw[8], traw[8];
#pragma unroll
        for (int j = 0; j < 8; j++) hraw[j] = hp[j];
#pragma unroll
        for (int j = 0; j < 8; j++) traw[j] = tp[j];
        const __half2* h2 = (const __half2*)hraw;
        const __half2* t2 = (const __half2*)traw;
        float logit[KK];
#pragma unroll
        for (int k = 0; k < KK; k++) logit[k] = 0.f;
        float dot = 0.f;
#pragma unroll 4
        for (int l4 = 0; l4 < 16; l4++) {
            float2 ha = __half22float2(h2[2 * l4]), hb = __half22float2(h2[2 * l4 + 1]);
            float2 ta = __half22float2(t2[2 * l4]), tb = __half22float2(t2[2 * l4 + 1]);
            float p0 = ha.x * ta.x, p1 = ha.y * ta.y, p2 = hb.x * tb.x, p3 = hb.y * tb.y;
            dot += p0 + p1 + p2 + p3;
            const float* w = &Wl[l4 * 4 * KK];
#pragma unroll
            for (int k = 0; k < KK; k++)
                logit[k] += p0 * w[k] + p1 * w[KK + k] + p2 * w[2 * KK + k] + p3 * w[3 * KK + k];
        }
        float m = logit[0];
#pragma unroll
        for (int k = 1; k < KK; k++) m = fmaxf(m, logit[k]);
        float ssum = 0.f;
#pragma unroll
        for (int k = 0; k < KK; k++) { float ev = __expf(logit[k] - m); logit[k] = ev; ssum += ev; }
        float scale = 0.5f * (dot + 1.0f) / ssum;
        uint4 pk[4];
        unsigned int* u = (unsigned int*)pk;
#pragma unroll
        for (int k2 = 0; k2 < 16; k2++) {
            __half2 hh = __floats2half2_rn(logit[2 * k2] * scale, logit[2 * k2 + 1] * scale);
            u[k2] = *reinterpret_cast<const unsigned int*>(&hh);
        }
        uint4* dst = (uint4*)(c_out + (size_t)p * KK);
#pragma unroll
        for (int q = 0; q < 4; q++) dst[q] = pk[q];
    }
}

// ---------------- pass B: agg -> recip[NN][32] (single sweep over c) ----------------
__global__ __launch_bounds__(256) void k_passB(const int* __restrict__ rp,
                                               const int* __restrict__ map,
                                               int nsplit, int peoff,
                                               const __half* __restrict__ c,
                                               float* __restrict__ recip, int n) {
    int gid = blockIdx.x * blockDim.x + threadIdx.x;
    int node = gid >> 3, j = gid & 7;
    if (node >= n) return;
    bool use_map = (map != nullptr) && (node >= nsplit);
    int p0 = rp[node], p1 = rp[node + 1];
    const uint2* cp = (const uint2*)c;
    float4 agg = make_float4(0.f, 0.f, 0.f, 0.f);
    for (int p = p0; p < p1; p++) {
        int idx = use_map ? map[p - peoff] : p;
        uint2 v = cp[(size_t)idx * 8 + j];
        float2 fa = __half22float2(*reinterpret_cast<const __half2*>(&v.x));
        float2 fb = __half22float2(*reinterpret_cast<const __half2*>(&v.y));
        agg.x += fa.x; agg.y += fa.y; agg.z += fb.x; agg.w += fb.y;
    }
    float4 rec;
    rec.x = (agg.x != 0.f) ? 1.f / agg.x : 0.f;
    rec.y = (agg.y != 0.f) ? 1.f / agg.y : 0.f;
    rec.z = (agg.z != 0.f) ? 1.f / agg.z : 0.f;
    rec.w = (agg.w != 0.f) ? 1.f / agg.w : 0.f;
    ((float4*)recip)[(size_t)node * 8 + j] = rec;
}

// readlane-based broadcast of packed component (l compile-time)
#define PRD(a0, a1, a2, a3, l) \
    rdlane(((l) & 3) == 0 ? (a0) : ((l) & 3) == 1 ? (a1) : ((l) & 3) == 2 ? (a2) : (a3), (l) >> 2)

// ---------------- fused UI: g1 + t1(inline intent-w) + z-preact; 64 rows/block ----------
__global__ __launch_bounds__(512) void k_fused_ui(
        const int* __restrict__ rp, const int* __restrict__ col,
        const float* __restrict__ gw, const __half* __restrict__ cbuf,
        const int* __restrict__ mUI, const float* __restrict__ recip,
        const float* __restrict__ Wd_g, const float* __restrict__ Wd_t,
        const float* __restrict__ b2, const __half* __restrict__ x,
        __half* __restrict__ gs, __half* __restrict__ ts,
        float* __restrict__ zp, int nrows) {
    __shared__ float Wg[DD * DD];
    __shared__ float Wt[DD * DD];
    for (int i = threadIdx.x; i < DD * DD; i += 512) { Wg[i] = Wd_g[i]; Wt[i] = Wd_t[i]; }
    __syncthreads();
    int wid = threadIdx.x >> 6, lane = threadIdx.x & 63;
    int sub = lane & 15, grp = lane >> 4;
    float b2v = b2[lane];
    const uint2* xq = (const uint2*)x;
    const unsigned int* cu = (const unsigned int*)cbuf;
    int rbase = blockIdx.x * ROWS_PB + wid * 8;
    for (int rr = 0; rr < 8; rr++) {
        int r = rbase + rr;
        if (r >= nrows) break;
        float2 rc = *(const float2*)(recip + (size_t)r * KK + 2 * sub);
        bool item = (r >= NU);   // wave-uniform
        float g0 = 0, g1 = 0, g2 = 0, g3 = 0, t0 = 0, t1 = 0, t2 = 0, t3 = 0;
        float rsacc = 0.f;
        int e = rp[r], e1 = rp[r + 1];
        for (; e + 8 <= e1; e += 8) {
#pragma unroll
            for (int u = 0; u < 2; u++) {
                int idx = e + 4 * u + grp;
                int cc = col[idx];
                float wg = gw[idx];
                int ci = item ? mUI[idx - EUI] : idx;
                unsigned int cv = cu[(size_t)ci * 16 + sub];
                float2 cf = __half22float2(*(const __half2*)&cv);
                float pd = fmaf(cf.x, rc.x, cf.y * rc.y);
                pd += __shfl_xor(pd, 1, 64); pd += __shfl_xor(pd, 2, 64);
                pd += __shfl_xor(pd, 4, 64); pd += __shfl_xor(pd, 8, 64);
                float wt = pd * (1.0f / KK);
                rsacc += wt;
                uint2 raw = xq[(size_t)cc * 16 + sub];
                float2 xa = __half22float2(*(const __half2*)&raw.x);
                float2 xb = __half22float2(*(const __half2*)&raw.y);
                g0 += wg * xa.x; g1 += wg * xa.y; g2 += wg * xb.x; g3 += wg * xb.y;
                t0 += wt * xa.x; t1 += wt * xa.y; t2 += wt * xb.x; t3 += wt * xb.y;
            }
        }
        for (; e < e1; e += 4) {
            int idx = e + grp;
            if (idx < e1) {   // group-uniform guard
                int cc = col[idx];
                float wg = gw[idx];
                int ci = item ? mUI[idx - EUI] : idx;
                unsigned int cv = cu[(size_t)ci * 16 + sub];
                float2 cf = __half22float2(*(const __half2*)&cv);
                float pd = fmaf(cf.x, rc.x, cf.y * rc.y);
                pd += __shfl_xor(pd, 1, 64); pd += __shfl_xor(pd, 2, 64);
                pd += __shfl_xor(pd, 4, 64); pd += __shfl_xor(pd, 8, 64);
                float wt = pd * (1.0f / KK);
                rsacc += wt;
                uint2 raw = xq[(size_t)cc * 16 + sub];
                float2 xa = __half22float2(*(const __half2*)&raw.x);
                float2 xb = __half22float2(*(const __half2*)&raw.y);
                g0 += wg * xa.x; g1 += wg * xa.y; g2 += wg * xb.x; g3 += wg * xb.y;
                t0 += wt * xa.x; t1 += wt * xa.y; t2 += wt * xb.x; t3 += wt * xb.y;
            }
        }
#pragma unroll
        for (int off = 16; off <= 32; off <<= 1) {
            g0 += __shfl_xor(g0, off, 64); g1 += __shfl_xor(g1, off, 64);
            g2 += __shfl_xor(g2, off, 64); g3 += __shfl_xor(g3, off, 64);
            t0 += __shfl_xor(t0, off, 64); t1 += __shfl_xor(t1, off, 64);
            t2 += __shfl_xor(t2, off, 64); t3 += __shfl_xor(t3, off, 64);
            rsacc += __shfl_xor(rsacc, off, 64);
        }
        float rsv = (rsacc != 0.f) ? 1.0f / rsacc : 0.f;
        t0 *= rsv; t1 *= rsv; t2 *= rsv; t3 *= rsv;
        float ss = t0 * t0 + t1 * t1 + t2 * t2 + t3 * t3;
        ss += __shfl_xor(ss, 1, 64); ss += __shfl_xor(ss, 2, 64);
        ss += __shfl_xor(ss, 4, 64); ss += __shfl_xor(ss, 8, 64);
        float inv_n = 1.0f / fmaxf(sqrtf(ss), 1e-12f);
        t0 *= inv_n; t1 *= inv_n; t2 *= inv_n; t3 *= inv_n;
        float zv = b2v;
#pragma unroll
        for (int l = 0; l < DD; l++) {
            float gl = PRD(g0, g1, g2, g3, l);
            float tl = PRD(t0, t1, t2, t3, l);
            zv += gl * Wg[l * DD + lane] + tl * Wt[l * DD + lane];
        }
        float ga0 = __shfl(g0, lane >> 2, 64), ga1 = __shfl(g1, lane >> 2, 64);
        float ga2 = __shfl(g2, lane >> 2, 64), ga3 = __shfl(g3, lane >> 2, 64);
        float ta0 = __shfl(t0, lane >> 2, 64), ta1 = __shfl(t1, lane >> 2, 64);
        float ta2 = __shfl(t2, lane >> 2, 64), ta3 = __shfl(t3, lane >> 2, 64);
        int j = lane & 3;
        float gsv = j == 0 ? ga0 : j == 1 ? ga1 : j == 2 ? ga2 : ga3;
        float tsv = j == 0 ? ta0 : j == 1 ? ta1 : j == 2 ? ta2 : ta3;
        size_t oi = (size_t)r * DD + lane;
        gs[oi] = __float2half(gsv);
        ts[oi] = __float2half(tsv);
        zp[oi] = zv;
    }
}

// ---------------- fused finalize: g2 + t2(inline intent-w) + gate + combine -------------
__global__ __launch_bounds__(512) void k_fused_fin(
        const int* __restrict__ rp, const int* __restrict__ col,
        const float* __restrict__ bw, const __half* __restrict__ cbuf,
        const float* __restrict__ recip,
        const float* __restrict__ W1, const float* __restrict__ W3,
        const __half* __restrict__ x, const __half* __restrict__ gs,
        const __half* __restrict__ ts, const float* __restrict__ zp,
        __half* __restrict__ xh_out, float* __restrict__ acc, int nrows) {
    __shared__ float Wa[DD * DD];
    __shared__ float Wb[DD * DD];
    for (int i = threadIdx.x; i < DD * DD; i += 512) { Wa[i] = W1[i]; Wb[i] = W3[i]; }
    __syncthreads();
    int wid = threadIdx.x >> 6, lane = threadIdx.x & 63;
    int sub = lane & 15, grp = lane >> 4;
    const uint2* xq = (const uint2*)x;
    const unsigned int* cu = (const unsigned int*)cbuf;
    int rbase = blockIdx.x * ROWS_PB + wid * 8;
    for (int rr = 0; rr < 8; rr++) {
        int r = rbase + rr;
        if (r >= nrows) break;
        float2 rc = *(const float2*)(recip + (size_t)r * KK + 2 * sub);
        float g0 = 0, g1 = 0, g2 = 0, g3 = 0, t0 = 0, t1 = 0, t2 = 0, t3 = 0;
        float rsacc = 0.f;
        int e = rp[r], e1 = rp[r + 1];
        for (; e + 8 <= e1; e += 8) {
#pragma unroll
            for (int u = 0; u < 2; u++) {
                int idx = e + 4 * u + grp;
                int cc = col[idx];
                float wg = bw[idx];
                unsigned int cv = cu[(size_t)idx * 16 + sub];
                float2 cf = __half22float2(*(const __half2*)&cv);
                float pd = fmaf(cf.x, rc.x, cf.y * rc.y);
                pd += __shfl_xor(pd, 1, 64); pd += __shfl_xor(pd, 2, 64);
                pd += __shfl_xor(pd, 4, 64); pd += __shfl_xor(pd, 8, 64);
                float wt = pd * (1.0f / KK);
                rsacc += wt;
                uint2 raw = xq[(size_t)cc * 16 + sub];
                float2 xa = __half22float2(*(const __half2*)&raw.x);
                float2 xb = __half22float2(*(const __half2*)&raw.y);
                g0 += wg * xa.x; g1 += wg * xa.y; g2 += wg * xb.x; g3 += wg * xb.y;
                t0 += wt * xa.x; t1 += wt * xa.y; t2 += wt * xb.x; t3 += wt * xb.y;
            }
        }
        for (; e < e1; e += 4) {
            int idx = e + grp;
            if (idx < e1) {
                int cc = col[idx];
                float wg = bw[idx];
                unsigned int cv = cu[(size_t)idx * 16 + sub];
                float2 cf = __half22float2(*(const __half2*)&cv);
                float pd = fmaf(cf.x, rc.x, cf.y * rc.y);
                pd += __shfl_xor(pd, 1, 64); pd += __shfl_xor(pd, 2, 64);
                pd += __shfl_xor(pd, 4, 64); pd += __shfl_xor(pd, 8, 64);
                float wt = pd * (1.0f / KK);
                rsacc += wt;
                uint2 raw = xq[(size_t)cc * 16 + sub];
                float2 xa = __half22float2(*(const __half2*)&raw.x);
                float2 xb = __half22float2(*(const __half2*)&raw.y);
                g0 += wg * xa.x; g1 += wg * xa.y; g2 += wg * xb.x; g3 += wg * xb.y;
                t0 += wt * xa.x; t1 += wt * xa.y; t2 += wt * xb.x; t3 += wt * xb.y;
            }
        }
#pragma unroll
        for (int off = 16; off <= 32; off <<= 1) {
            g0 += __shfl_xor(g0, off, 64); g1 += __shfl_xor(g1, off, 64);
            g2 += __shfl_xor(g2, off, 64); g3 += __shfl_xor(g3, off, 64);
            t0 += __shfl_xor(t0, off, 64); t1 += __shfl_xor(t1, off, 64);
            t2 += __shfl_xor(t2, off, 64); t3 += __shfl_xor(t3, off, 64);
            rsacc += __shfl_xor(rsacc, off, 64);
        }
        float rsv = (rsacc != 0.f) ? 1.0f / rsacc : 0.f;
        t0 *= rsv; t1 *= rsv; t2 *= rsv; t3 *= rsv;
        float ss = t0 * t0 + t1 * t1 + t2 * t2 + t3 * t3;
        ss += __shfl_xor(ss, 1, 64); ss += __shfl_xor(ss, 2, 64);
        ss += __shfl_xor(ss, 4, 64); ss += __shfl_xor(ss, 8, 64);
        float inv_n = 1.0f / fmaxf(sqrtf(ss), 1e-12f);
        t0 *= inv_n; t1 *= inv_n; t2 *= inv_n; t3 *= inv_n;
        // add stored g1/t1 rows (fp16, 4 dims/lane)
        uint2 gp2 = ((const uint2*)(gs + (size_t)r * DD))[sub];
        uint2 tp2 = ((const uint2*)(ts + (size_t)r * DD))[sub];
        float2 gpa = __half22float2(*(const __half2*)&gp2.x);
        float2 gpb = __half22float2(*(const __half2*)&gp2.y);
        float2 tpa = __half22float2(*(const __half2*)&tp2.x);
        float2 tpb = __half22float2(*(const __half2*)&tp2.y);
        float gf0 = gpa.x + g0, gf1 = gpa.y + g1, gf2 = gpb.x + g2, gf3 = gpb.y + g3;
        float tf0 = tpa.x + t0, tf1 = tpa.y + t1, tf2 = tpb.x + t2, tf3 = tpb.y + t3;
        size_t oi = (size_t)r * DD + lane;
        float zv = zp[oi];
#pragma unroll
        for (int l = 0; l < DD; l++) {
            float gl = PRD(gf0, gf1, gf2, gf3, l);
            float tl = PRD(tf0, tf1, tf2, tf3, l);
            zv += gl * Wa[l * DD + lane] + tl * Wb[l * DD + lane];
        }
        float ga0 = __shfl(gf0, lane >> 2, 64), ga1 = __shfl(gf1, lane >> 2, 64);
        float ga2 = __shfl(gf2, lane >> 2, 64), ga3 = __shfl(gf3, lane >> 2, 64);
        float ta0 = __shfl(tf0, lane >> 2, 64), ta1 = __shfl(tf1, lane >> 2, 64);
        float ta2 = __shfl(tf2, lane >> 2, 64), ta3 = __shfl(tf3, lane >> 2, 64);
        int j = lane & 3;
        float gfin = j == 0 ? ga0 : j == 1 ? ga1 : j == 2 ? ga2 : ga3;
        float tfin = j == 0 ? ta0 : j == 1 ? ta1 : j == 2 ? ta2 : ta3;
        float gate = 1.0f / (1.0f + __expf(-zv));
        float xn = gate * gfin + (1.0f - gate) * tfin;
        xh_out[oi] = __float2half(xn);
        acc[oi] += xn;
    }
}

// ---------------- host launcher ----------------

extern "C" void kernel_launch(void* const* d_in, const int* in_sizes, int n_in,
                              void* d_out, int out_size, void* d_ws, size_t ws_size,
                              hipStream_t stream) {
    const float* user_emb = (const float*)d_in[0];
    const float* item_emb = (const float*)d_in[1];
    const float* intents  = (const float*)d_in[2];
    const float* W2       = (const float*)d_in[3];
    const float* b2       = (const float*)d_in[4];
    const float* uu_w     = (const float*)d_in[5];
    const float* ii_w     = (const float*)d_in[6];
    const int*   ui_u     = (const int*)d_in[7];
    const int*   ui_i     = (const int*)d_in[8];
    const int*   uu_h     = (const int*)d_in[9];
    const int*   uu_t     = (const int*)d_in[10];
    const int*   ii_h     = (const int*)d_in[11];
    const int*   ii_t     = (const int*)d_in[12];
    float* acc = (float*)d_out;

    char* pw = (char*)d_ws;
    auto allocb = [&](size_t nbytes) -> char* {
        char* r = pw;
        pw += (nbytes + 255) & ~(size_t)255;
        return r;
    };
    // ~238 MB total
    __half* gs   = (__half*)allocb((size_t)NN * DD * 2);
    __half* ts   = (__half*)allocb((size_t)NN * DD * 2);
    float* zp    = (float*)allocb((size_t)NN * DD * 4);
    __half* xh0  = (__half*)allocb((size_t)NN * DD * 2);
    __half* xh1  = (__half*)allocb((size_t)NN * DD * 2);
    __half* c    = (__half*)allocb((size_t)EUI * KK * 2);  // 64 MB; build scratch aliases here
    float* recip = (float*)allocb((size_t)NN * KK * 4);    // 19.2 MB
    float* dinv  = (float*)allocb((size_t)NN * 4);
    float* iuu   = (float*)allocb((size_t)NU * 4);
    float* iii   = (float*)allocb((size_t)NI * 4);
    float* Wd_g  = (float*)allocb((size_t)DD * DD * 4);
    float* Wd_t  = (float*)allocb((size_t)DD * DD * 4);
    int* rp_u    = (int*)allocb(((size_t)NU + 1) * 4);
    int* rp_i    = (int*)allocb(((size_t)NI + 1) * 4);
    int* rp_uu   = (int*)allocb(((size_t)NU + 1) * 4);
    int* rp_ii   = (int*)allocb(((size_t)NI + 1) * 4);
    int* rp_ui   = (int*)allocb(((size_t)NN + 1) * 4);
    int* rp_s    = (int*)allocb(((size_t)NN + 1) * 4);
    int* headU   = (int*)allocb((size_t)EUI * 4);
    int* colUI   = (int*)allocb((size_t)2 * EUI * 4);
    int* head_s  = (int*)allocb((size_t)(EUU + EII) * 4);
    int* col_s   = (int*)allocb((size_t)(EUU + EII) * 4);
    float* bw_s  = (float*)allocb((size_t)(EUU + EII) * 4);
    int* mUI     = (int*)allocb((size_t)EUI * 4);
    float* gwUI  = (float*)allocb((size_t)2 * EUI * 4);

    char* ca = (char*)c;
    int* cur    = (int*)ca;  ca += ((size_t)NU * 4 + 255) & ~(size_t)255;
    int* lst_u  = (int*)ca;  ca += ((size_t)EUI * 4 + 255) & ~(size_t)255;
    int* lst_i  = (int*)ca;  ca += ((size_t)EUI * 4 + 255) & ~(size_t)255;
    int* lst_uu = (int*)ca;  ca += ((size_t)EUU * 4 + 255) & ~(size_t)255;
    int* lst_ii = (int*)ca;  ca += ((size_t)EII * 4 + 255) & ~(size_t)255;
    int* posU   = (int*)ca;

    const int B = 256;

    auto build_csr = [&](const int* h, int E, int n, int* rp, int* lst) {
        hipMemsetAsync(cur, 0, (size_t)n * 4, stream);
        k_count<<<cdiv(E, B), B, 0, stream>>>(h, cur, E);
        k_scan<<<1, 1024, 0, stream>>>(cur, rp, n);
        hipMemsetAsync(cur, 0, (size_t)n * 4, stream);
        k_scatter<<<cdiv(E, B), B, 0, stream>>>(h, rp, cur, lst, E);
    };

    build_csr(ui_u, EUI, NU, rp_u, lst_u);
    build_csr(ui_i, EUI, NI, rp_i, lst_i);
    build_csr(uu_h, EUU, NU, rp_uu, lst_uu);
    build_csr(ii_h, EII, NI, rp_ii, lst_ii);
    k_dinv<<<cdiv(NN, B), B, 0, stream>>>(rp_u, rp_i, dinv);
    k_rowsum_inv<<<cdiv(NU, B), B, 0, stream>>>(rp_uu, lst_uu, uu_w, iuu, NU);
    k_rowsum_inv<<<cdiv(NI, B), B, 0, stream>>>(rp_ii, lst_ii, ii_w, iii, NI);
    k_build_rp2<<<cdiv(NN + 1, B), B, 0, stream>>>(rp_u, rp_i, rp_uu, rp_ii, rp_ui, rp_s);
    k_build_ui<<<cdiv(EUI, B), B, 0, stream>>>(lst_u, ui_u, ui_i, headU, colUI, EUI);
    k_build_colI<<<cdiv(EUI, B), B, 0, stream>>>(lst_i, ui_u, colUI, EUI);
    k_posU<<<cdiv(EUI, B), B, 0, stream>>>(lst_u, posU, EUI);
    k_mapUI<<<cdiv(EUI, B), B, 0, stream>>>(lst_i, posU, mUI, EUI);
    k_build_s<<<cdiv(EUU, B), B, 0, stream>>>(lst_uu, uu_h, uu_t, uu_w, iuu, 0, 0,
                                              head_s, col_s, bw_s, EUU);
    k_build_s<<<cdiv(EII, B), B, 0, stream>>>(lst_ii, ii_h, ii_t, ii_w, iii, NU, EUU,
                                              head_s, col_s, bw_s, EII);
    k_build_gw<<<cdiv(NN, B), B, 0, stream>>>(rp_ui, colUI, dinv, gwUI, NN);
    k_wdiff<<<cdiv(DD * DD, B), B, 0, stream>>>(W2, Wd_g, Wd_t);
    k_init<<<cdiv((long)NN * DD, B), B, 0, stream>>>(user_emb, item_emb, xh0, acc);

    for (int layer = 0; layer < 2; ++layer) {
        const __half* xin = (layer == 0) ? xh0 : xh1;
        __half* xout = (layer == 0) ? xh1 : xh0;

        // ---- UI phase ----
        k_passA<<<1024, B, 0, stream>>>(headU, colUI, xin, intents, c, EUI);
        k_passB<<<cdiv((long)NN * 8, B), B, 0, stream>>>(rp_ui, mUI, NU, EUI, c, recip, NN);
        k_fused_ui<<<cdiv(NN, ROWS_PB), 512, 0, stream>>>(rp_ui, colUI, gwUI, c, mUI, recip,
                                                          Wd_g, Wd_t, b2, xin, gs, ts, zp, NN);

        // ---- UU+II phase ----
        k_passA<<<1024, B, 0, stream>>>(head_s, col_s, xin, intents, c, EUU + EII);
        k_passB<<<cdiv((long)NN * 8, B), B, 0, stream>>>(rp_s, nullptr, 0, 0, c, recip, NN);
        k_fused_fin<<<cdiv(NN, ROWS_PB), 512, 0, stream>>>(rp_s, col_s, bw_s, c, recip,
                                                           W2 + DD * DD, W2 + 3 * DD * DD,
                                                           xin, gs, ts, zp, xout, acc, NN);
    }
}

// Round 12
// 2205.897 us; speedup vs baseline: 1.4724x; 1.0128x over previous
//
#include <hip/hip_runtime.h>
#include <hip/hip_fp16.h>

#define NU 100000
#define NI 50000
#define NN 150000
#define DD 64
#define KK 32
#define EUI 1000000
#define EUU 500000
#define EII 500000
#define ROWS_PB 64

static inline int cdiv(long a, int b) { return (int)((a + b - 1) / b); }

__device__ __forceinline__ float rdlane(float v, int l) {
    return __int_as_float(__builtin_amdgcn_readlane(__float_as_int(v), l));
}

// ---------------- CSR build ----------------

__global__ void k_count(const int* __restrict__ h, int* __restrict__ cnt, int E) {
    int e = blockIdx.x * blockDim.x + threadIdx.x;
    if (e < E) atomicAdd(&cnt[h[e]], 1);
}

__global__ __launch_bounds__(1024) void k_scan(const int* __restrict__ cnt,
                                               int* __restrict__ rp, int n) {
    __shared__ int wsum[16];
    __shared__ int carry_s;
    int tid = threadIdx.x;
    int lane = tid & 63, wid = tid >> 6;
    if (tid == 0) carry_s = 0;
    __syncthreads();
    for (int base = 0; base < n; base += 1024) {
        int i = base + tid;
        int v = (i < n) ? cnt[i] : 0;
        int s = v;
#pragma unroll
        for (int off = 1; off < 64; off <<= 1) {
            int t = __shfl_up(s, off, 64);
            if (lane >= off) s += t;
        }
        if (lane == 63) wsum[wid] = s;
        __syncthreads();
        int woff = 0, total = 0;
#pragma unroll
        for (int w = 0; w < 16; w++) { int ws = wsum[w]; total += ws; if (w < wid) woff += ws; }
        int carry = carry_s;
        if (i < n) rp[i] = carry + woff + (s - v);
        __syncthreads();
        if (tid == 0) carry_s = carry + total;
        __syncthreads();
    }
    if (tid == 0) rp[n] = carry_s;
}

__global__ void k_scatter(const int* __restrict__ h, const int* __restrict__ rp,
                          int* __restrict__ cur, int* __restrict__ lst, int E) {
    int e = blockIdx.x * blockDim.x + threadIdx.x;
    if (e >= E) return;
    int r = h[e];
    int p = rp[r] + atomicAdd(&cur[r], 1);
    lst[p] = e;
}

__global__ void k_dinv(const int* __restrict__ rpu, const int* __restrict__ rpi,
                       float* __restrict__ dinv) {
    int t = blockIdx.x * blockDim.x + threadIdx.x;
    if (t >= NN) return;
    int deg = (t < NU) ? rpu[t + 1] - rpu[t] : rpi[t - NU + 1] - rpi[t - NU];
    dinv[t] = deg > 0 ? rsqrtf((float)deg) : 0.0f;
}

__global__ void k_rowsum_inv(const int* __restrict__ rp, const int* __restrict__ lst,
                             const float* __restrict__ w, float* __restrict__ out, int n) {
    int r = blockIdx.x * blockDim.x + threadIdx.x;
    if (r >= n) return;
    float s = 0.f;
    int e1 = rp[r + 1];
    for (int e = rp[r]; e < e1; e++) s += w[lst[e]];
    out[r] = (s != 0.0f) ? 1.0f / s : 0.0f;
}

__global__ void k_wdiff(const float* __restrict__ W2, float* __restrict__ Wd_g,
                        float* __restrict__ Wd_t) {
    int i = blockIdx.x * blockDim.x + threadIdx.x;
    if (i >= DD * DD) return;
    Wd_g[i] = W2[i] - W2[DD * DD + i];
    Wd_t[i] = W2[2 * DD * DD + i] - W2[3 * DD * DD + i];
}

__global__ void k_init(const float* __restrict__ ue, const float* __restrict__ ie,
                       __half* __restrict__ xh, float* __restrict__ acc) {
    size_t i = (size_t)blockIdx.x * blockDim.x + threadIdx.x;
    if (i >= (size_t)NN * DD) return;
    float v = (i < (size_t)NU * DD) ? ue[i] : ie[i - (size_t)NU * DD];
    xh[i] = __float2half(v);
    acc[i] = v;
}

// ---------------- map-building kernels (x-independent, run once) ----------------

__global__ void k_posU(const int* __restrict__ lst, int* __restrict__ pos, int E) {
    int p = blockIdx.x * blockDim.x + threadIdx.x;
    if (p < E) pos[lst[p]] = p;
}

__global__ void k_mapUI(const int* __restrict__ lst_i, const int* __restrict__ posU,
                        int* __restrict__ mUI, int E) {
    int p = blockIdx.x * blockDim.x + threadIdx.x;
    if (p < E) mUI[p] = posU[lst_i[p]];
}

__global__ void k_build_ui(const int* __restrict__ lst_u, const int* __restrict__ ui_u,
                           const int* __restrict__ ui_i, int* __restrict__ headU,
                           int* __restrict__ colUI, int E) {
    int p = blockIdx.x * blockDim.x + threadIdx.x;
    if (p >= E) return;
    int e = lst_u[p];
    headU[p] = ui_u[e];
    colUI[p] = ui_i[e] + NU;
}

__global__ void k_build_colI(const int* __restrict__ lst_i, const int* __restrict__ ui_u,
                             int* __restrict__ colUI, int E) {
    int p = blockIdx.x * blockDim.x + threadIdx.x;
    if (p < E) colUI[EUI + p] = ui_u[lst_i[p]];
}

__global__ void k_build_rp2(const int* __restrict__ rp_u, const int* __restrict__ rp_i,
                            const int* __restrict__ rp_uu, const int* __restrict__ rp_ii,
                            int* __restrict__ rp_ui, int* __restrict__ rp_s) {
    int t = blockIdx.x * blockDim.x + threadIdx.x;
    if (t > NN) return;
    rp_ui[t] = (t <= NU) ? rp_u[t] : rp_i[t - NU] + EUI;
    rp_s[t]  = (t <= NU) ? rp_uu[t] : rp_ii[t - NU] + EUU;
}

__global__ void k_build_gw(const int* __restrict__ rp, const int* __restrict__ col,
                           const float* __restrict__ dinv, float* __restrict__ gw, int n) {
    int r = blockIdx.x * blockDim.x + threadIdx.x;
    if (r >= n) return;
    float dh = dinv[r];
    int e1 = rp[r + 1];
    for (int p = rp[r]; p < e1; p++) gw[p] = dh * dinv[col[p]];
}

__global__ void k_build_s(const int* __restrict__ lst, const int* __restrict__ eh,
                          const int* __restrict__ et, const float* __restrict__ ew,
                          const float* __restrict__ inv, int off, int peo,
                          int* __restrict__ head, int* __restrict__ col,
                          float* __restrict__ bw, int E) {
    int p = blockIdx.x * blockDim.x + threadIdx.x;
    if (p >= E) return;
    int e = lst[p];
    int h = eh[e];
    head[peo + p] = h + off;
    col[peo + p] = et[e] + off;
    bw[peo + p] = ew[e] * inv[h];
}

// ---------------- pass A (CSR order, grid-stride): c[p] = alpha * dist, fp16 -----------

__global__ __launch_bounds__(256) void k_passA(
        const int* __restrict__ head, const int* __restrict__ col,
        const __half* __restrict__ x, const float* __restrict__ intents,
        __half* __restrict__ c_out, int E) {
    __shared__ float Wl[DD * KK];
    for (int idx = threadIdx.x; idx < DD * KK; idx += blockDim.x) Wl[idx] = intents[idx];
    __syncthreads();
    int stride = gridDim.x * blockDim.x;
    for (int p = blockIdx.x * blockDim.x + threadIdx.x; p < E; p += stride) {
        const uint4* hp = (const uint4*)(x + (size_t)head[p] * DD);
        const uint4* tp = (const uint4*)(x + (size_t)col[p] * DD);
        uint4 hraw[8], traw[8];
#pragma unroll
        for (int j = 0; j < 8; j++) hraw[j] = hp[j];
#pragma unroll
        for (int j = 0; j < 8; j++) traw[j] = tp[j];
        const __half2* h2 = (const __half2*)hraw;
        const __half2* t2 = (const __half2*)traw;
        float logit[KK];
#pragma unroll
        for (int k = 0; k < KK; k++) logit[k] = 0.f;
        float dot = 0.f;
#pragma unroll 4
        for (int l4 = 0; l4 < 16; l4++) {
            float2 ha = __half22float2(h2[2 * l4]), hb = __half22float2(h2[2 * l4 + 1]);
            float2 ta = __half22float2(t2[2 * l4]), tb = __half22float2(t2[2 * l4 + 1]);
            float p0 = ha.x * ta.x, p1 = ha.y * ta.y, p2 = hb.x * tb.x, p3 = hb.y * tb.y;
            dot += p0 + p1 + p2 + p3;
            const float* w = &Wl[l4 * 4 * KK];
#pragma unroll
            for (int k = 0; k < KK; k++)
                logit[k] += p0 * w[k] + p1 * w[KK + k] + p2 * w[2 * KK + k] + p3 * w[3 * KK + k];
        }
        float m = logit[0];
#pragma unroll
        for (int k = 1; k < KK; k++) m = fmaxf(m, logit[k]);
        float ssum = 0.f;
#pragma unroll
        for (int k = 0; k < KK; k++) { float ev = __expf(logit[k] - m); logit[k] = ev; ssum += ev; }
        float scale = 0.5f * (dot + 1.0f) / ssum;
        uint4 pk[4];
        unsigned int* u = (unsigned int*)pk;
#pragma unroll
        for (int k2 = 0; k2 < 16; k2++) {
            __half2 hh = __floats2half2_rn(logit[2 * k2] * scale, logit[2 * k2 + 1] * scale);
            u[k2] = *reinterpret_cast<const unsigned int*>(&hh);
        }
        uint4* dst = (uint4*)(c_out + (size_t)p * KK);
#pragma unroll
        for (int q = 0; q < 4; q++) dst[q] = pk[q];
    }
}

// readlane-based broadcast of packed component (l compile-time)
#define PRD(a0, a1, a2, a3, l) \
    rdlane(((l) & 3) == 0 ? (a0) : ((l) & 3) == 1 ? (a1) : ((l) & 3) == 2 ? (a2) : (a3), (l) >> 2)

// ---------------- fused UI: inline agg + g1 + t1 + z-preact; 64 rows/block --------------
__global__ __launch_bounds__(512) void k_fused_ui(
        const int* __restrict__ rp, const int* __restrict__ col,
        const float* __restrict__ gw, const __half* __restrict__ cbuf,
        const int* __restrict__ mUI,
        const float* __restrict__ Wd_g, const float* __restrict__ Wd_t,
        const float* __restrict__ b2, const __half* __restrict__ x,
        __half* __restrict__ gs, __half* __restrict__ ts,
        float* __restrict__ zp, int nrows) {
    __shared__ float Wg[DD * DD];
    __shared__ float Wt[DD * DD];
    for (int i = threadIdx.x; i < DD * DD; i += 512) { Wg[i] = Wd_g[i]; Wt[i] = Wd_t[i]; }
    __syncthreads();
    int wid = threadIdx.x >> 6, lane = threadIdx.x & 63;
    int sub = lane & 15, grp = lane >> 4;
    float b2v = b2[lane];
    const uint2* xq = (const uint2*)x;
    const unsigned int* cu = (const unsigned int*)cbuf;
    int rbase = blockIdx.x * ROWS_PB + wid * 8;
    for (int rr = 0; rr < 8; rr++) {
        int r = rbase + rr;
        if (r >= nrows) break;
        bool item = (r >= NU);   // wave-uniform
        int e0 = rp[r], e1 = rp[r + 1];
        // ---- sweep 1: agg over row's c entries -> recip in-register ----
        float a0 = 0.f, a1 = 0.f;
        for (int e = e0; e < e1; e += 4) {
            int idx = e + grp;
            if (idx < e1) {
                int ci = item ? mUI[idx - EUI] : idx;
                unsigned int cv = cu[(size_t)ci * 16 + sub];
                float2 cf = __half22float2(*(const __half2*)&cv);
                a0 += cf.x; a1 += cf.y;
            }
        }
        a0 += __shfl_xor(a0, 16, 64); a0 += __shfl_xor(a0, 32, 64);
        a1 += __shfl_xor(a1, 16, 64); a1 += __shfl_xor(a1, 32, 64);
        float2 rc;
        rc.x = (a0 != 0.f) ? 1.f / a0 : 0.f;
        rc.y = (a1 != 0.f) ? 1.f / a1 : 0.f;
        // ---- sweep 2: weights + gather-accumulate ----
        float g0 = 0, g1 = 0, g2 = 0, g3 = 0, t0 = 0, t1 = 0, t2 = 0, t3 = 0;
        float rsacc = 0.f;
        int e = e0;
        for (; e + 8 <= e1; e += 8) {
#pragma unroll
            for (int u = 0; u < 2; u++) {
                int idx = e + 4 * u + grp;
                int cc = col[idx];
                float wg = gw[idx];
                int ci = item ? mUI[idx - EUI] : idx;
                unsigned int cv = cu[(size_t)ci * 16 + sub];
                float2 cf = __half22float2(*(const __half2*)&cv);
                float pd = fmaf(cf.x, rc.x, cf.y * rc.y);
                pd += __shfl_xor(pd, 1, 64); pd += __shfl_xor(pd, 2, 64);
                pd += __shfl_xor(pd, 4, 64); pd += __shfl_xor(pd, 8, 64);
                float wt = pd * (1.0f / KK);
                rsacc += wt;
                uint2 raw = xq[(size_t)cc * 16 + sub];
                float2 xa = __half22float2(*(const __half2*)&raw.x);
                float2 xb = __half22float2(*(const __half2*)&raw.y);
                g0 += wg * xa.x; g1 += wg * xa.y; g2 += wg * xb.x; g3 += wg * xb.y;
                t0 += wt * xa.x; t1 += wt * xa.y; t2 += wt * xb.x; t3 += wt * xb.y;
            }
        }
        for (; e < e1; e += 4) {
            int idx = e + grp;
            if (idx < e1) {
                int cc = col[idx];
                float wg = gw[idx];
                int ci = item ? mUI[idx - EUI] : idx;
                unsigned int cv = cu[(size_t)ci * 16 + sub];
                float2 cf = __half22float2(*(const __half2*)&cv);
                float pd = fmaf(cf.x, rc.x, cf.y * rc.y);
                pd += __shfl_xor(pd, 1, 64); pd += __shfl_xor(pd, 2, 64);
                pd += __shfl_xor(pd, 4, 64); pd += __shfl_xor(pd, 8, 64);
                float wt = pd * (1.0f / KK);
                rsacc += wt;
                uint2 raw = xq[(size_t)cc * 16 + sub];
                float2 xa = __half22float2(*(const __half2*)&raw.x);
                float2 xb = __half22float2(*(const __half2*)&raw.y);
                g0 += wg * xa.x; g1 += wg * xa.y; g2 += wg * xb.x; g3 += wg * xb.y;
                t0 += wt * xa.x; t1 += wt * xa.y; t2 += wt * xb.x; t3 += wt * xb.y;
            }
        }
#pragma unroll
        for (int off = 16; off <= 32; off <<= 1) {
            g0 += __shfl_xor(g0, off, 64); g1 += __shfl_xor(g1, off, 64);
            g2 += __shfl_xor(g2, off, 64); g3 += __shfl_xor(g3, off, 64);
            t0 += __shfl_xor(t0, off, 64); t1 += __shfl_xor(t1, off, 64);
            t2 += __shfl_xor(t2, off, 64); t3 += __shfl_xor(t3, off, 64);
            rsacc += __shfl_xor(rsacc, off, 64);
        }
        float rsv = (rsacc != 0.f) ? 1.0f / rsacc : 0.f;
        t0 *= rsv; t1 *= rsv; t2 *= rsv; t3 *= rsv;
        float ss = t0 * t0 + t1 * t1 + t2 * t2 + t3 * t3;
        ss += __shfl_xor(ss, 1, 64); ss += __shfl_xor(ss, 2, 64);
        ss += __shfl_xor(ss, 4, 64); ss += __shfl_xor(ss, 8, 64);
        float inv_n = 1.0f / fmaxf(sqrtf(ss), 1e-12f);
        t0 *= inv_n; t1 *= inv_n; t2 *= inv_n; t3 *= inv_n;
        float zv = b2v;
#pragma unroll
        for (int l = 0; l < DD; l++) {
            float gl = PRD(g0, g1, g2, g3, l);
            float tl = PRD(t0, t1, t2, t3, l);
            zv += gl * Wg[l * DD + lane] + tl * Wt[l * DD + lane];
        }
        float ga0 = __shfl(g0, lane >> 2, 64), ga1 = __shfl(g1, lane >> 2, 64);
        float ga2 = __shfl(g2, lane >> 2, 64), ga3 = __shfl(g3, lane >> 2, 64);
        float ta0 = __shfl(t0, lane >> 2, 64), ta1 = __shfl(t1, lane >> 2, 64);
        float ta2 = __shfl(t2, lane >> 2, 64), ta3 = __shfl(t3, lane >> 2, 64);
        int j = lane & 3;
        float gsv = j == 0 ? ga0 : j == 1 ? ga1 : j == 2 ? ga2 : ga3;
        float tsv = j == 0 ? ta0 : j == 1 ? ta1 : j == 2 ? ta2 : ta3;
        size_t oi = (size_t)r * DD + lane;
        gs[oi] = __float2half(gsv);
        ts[oi] = __float2half(tsv);
        zp[oi] = zv;
    }
}

// ---------------- fused finalize: inline agg + g2 + t2 + gate + combine -----------------
__global__ __launch_bounds__(512) void k_fused_fin(
        const int* __restrict__ rp, const int* __restrict__ col,
        const float* __restrict__ bw, const __half* __restrict__ cbuf,
        const float* __restrict__ W1, const float* __restrict__ W3,
        const __half* __restrict__ x, const __half* __restrict__ gs,
        const __half* __restrict__ ts, const float* __restrict__ zp,
        __half* __restrict__ xh_out, float* __restrict__ acc, int nrows) {
    __shared__ float Wa[DD * DD];
    __shared__ float Wb[DD * DD];
    for (int i = threadIdx.x; i < DD * DD; i += 512) { Wa[i] = W1[i]; Wb[i] = W3[i]; }
    __syncthreads();
    int wid = threadIdx.x >> 6, lane = threadIdx.x & 63;
    int sub = lane & 15, grp = lane >> 4;
    const uint2* xq = (const uint2*)x;
    const unsigned int* cu = (const unsigned int*)cbuf;
    int rbase = blockIdx.x * ROWS_PB + wid * 8;
    for (int rr = 0; rr < 8; rr++) {
        int r = rbase + rr;
        if (r >= nrows) break;
        int e0 = rp[r], e1 = rp[r + 1];
        // ---- sweep 1: agg (stream, CSR order) ----
        float a0 = 0.f, a1 = 0.f;
        for (int e = e0; e < e1; e += 4) {
            int idx = e + grp;
            if (idx < e1) {
                unsigned int cv = cu[(size_t)idx * 16 + sub];
                float2 cf = __half22float2(*(const __half2*)&cv);
                a0 += cf.x; a1 += cf.y;
            }
        }
        a0 += __shfl_xor(a0, 16, 64); a0 += __shfl_xor(a0, 32, 64);
        a1 += __shfl_xor(a1, 16, 64); a1 += __shfl_xor(a1, 32, 64);
        float2 rc;
        rc.x = (a0 != 0.f) ? 1.f / a0 : 0.f;
        rc.y = (a1 != 0.f) ? 1.f / a1 : 0.f;
        // ---- sweep 2 ----
        float g0 = 0, g1 = 0, g2 = 0, g3 = 0, t0 = 0, t1 = 0, t2 = 0, t3 = 0;
        float rsacc = 0.f;
        int e = e0;
        for (; e + 8 <= e1; e += 8) {
#pragma unroll
            for (int u = 0; u < 2; u++) {
                int idx = e + 4 * u + grp;
                int cc = col[idx];
                float wg = bw[idx];
                unsigned int cv = cu[(size_t)idx * 16 + sub];
                float2 cf = __half22float2(*(const __half2*)&cv);
                float pd = fmaf(cf.x, rc.x, cf.y * rc.y);
                pd += __shfl_xor(pd, 1, 64); pd += __shfl_xor(pd, 2, 64);
                pd += __shfl_xor(pd, 4, 64); pd += __shfl_xor(pd, 8, 64);
                float wt = pd * (1.0f / KK);
                rsacc += wt;
                uint2 raw = xq[(size_t)cc * 16 + sub];
                float2 xa = __half22float2(*(const __half2*)&raw.x);
                float2 xb = __half22float2(*(const __half2*)&raw.y);
                g0 += wg * xa.x; g1 += wg * xa.y; g2 += wg * xb.x; g3 += wg * xb.y;
                t0 += wt * xa.x; t1 += wt * xa.y; t2 += wt * xb.x; t3 += wt * xb.y;
            }
        }
        for (; e < e1; e += 4) {
            int idx = e + grp;
            if (idx < e1) {
                int cc = col[idx];
                float wg = bw[idx];
                unsigned int cv = cu[(size_t)idx * 16 + sub];
                float2 cf = __half22float2(*(const __half2*)&cv);
                float pd = fmaf(cf.x, rc.x, cf.y * rc.y);
                pd += __shfl_xor(pd, 1, 64); pd += __shfl_xor(pd, 2, 64);
                pd += __shfl_xor(pd, 4, 64); pd += __shfl_xor(pd, 8, 64);
                float wt = pd * (1.0f / KK);
                rsacc += wt;
                uint2 raw = xq[(size_t)cc * 16 + sub];
                float2 xa = __half22float2(*(const __half2*)&raw.x);
                float2 xb = __half22float2(*(const __half2*)&raw.y);
                g0 += wg * xa.x; g1 += wg * xa.y; g2 += wg * xb.x; g3 += wg * xb.y;
                t0 += wt * xa.x; t1 += wt * xa.y; t2 += wt * xb.x; t3 += wt * xb.y;
            }
        }
#pragma unroll
        for (int off = 16; off <= 32; off <<= 1) {
            g0 += __shfl_xor(g0, off, 64); g1 += __shfl_xor(g1, off, 64);
            g2 += __shfl_xor(g2, off, 64); g3 += __shfl_xor(g3, off, 64);
            t0 += __shfl_xor(t0, off, 64); t1 += __shfl_xor(t1, off, 64);
            t2 += __shfl_xor(t2, off, 64); t3 += __shfl_xor(t3, off, 64);
            rsacc += __shfl_xor(rsacc, off, 64);
        }
        float rsv = (rsacc != 0.f) ? 1.0f / rsacc : 0.f;
        t0 *= rsv; t1 *= rsv; t2 *= rsv; t3 *= rsv;
        float ss = t0 * t0 + t1 * t1 + t2 * t2 + t3 * t3;
        ss += __shfl_xor(ss, 1, 64); ss += __shfl_xor(ss, 2, 64);
        ss += __shfl_xor(ss, 4, 64); ss += __shfl_xor(ss, 8, 64);
        float inv_n = 1.0f / fmaxf(sqrtf(ss), 1e-12f);
        t0 *= inv_n; t1 *= inv_n; t2 *= inv_n; t3 *= inv_n;
        uint2 gp2 = ((const uint2*)(gs + (size_t)r * DD))[sub];
        uint2 tp2 = ((const uint2*)(ts + (size_t)r * DD))[sub];
        float2 gpa = __half22float2(*(const __half2*)&gp2.x);
        float2 gpb = __half22float2(*(const __half2*)&gp2.y);
        float2 tpa = __half22float2(*(const __half2*)&tp2.x);
        float2 tpb = __half22float2(*(const __half2*)&tp2.y);
        float gf0 = gpa.x + g0, gf1 = gpa.y + g1, gf2 = gpb.x + g2, gf3 = gpb.y + g3;
        float tf0 = tpa.x + t0, tf1 = tpa.y + t1, tf2 = tpb.x + t2, tf3 = tpb.y + t3;
        size_t oi = (size_t)r * DD + lane;
        float zv = zp[oi];
#pragma unroll
        for (int l = 0; l < DD; l++) {
            float gl = PRD(gf0, gf1, gf2, gf3, l);
            float tl = PRD(tf0, tf1, tf2, tf3, l);
            zv += gl * Wa[l * DD + lane] + tl * Wb[l * DD + lane];
        }
        float ga0 = __shfl(gf0, lane >> 2, 64), ga1 = __shfl(gf1, lane >> 2, 64);
        float ga2 = __shfl(gf2, lane >> 2, 64), ga3 = __shfl(gf3, lane >> 2, 64);
        float ta0 = __shfl(tf0, lane >> 2, 64), ta1 = __shfl(tf1, lane >> 2, 64);
        float ta2 = __shfl(tf2, lane >> 2, 64), ta3 = __shfl(tf3, lane >> 2, 64);
        int j = lane & 3;
        float gfin = j == 0 ? ga0 : j == 1 ? ga1 : j == 2 ? ga2 : ga3;
        float tfin = j == 0 ? ta0 : j == 1 ? ta1 : j == 2 ? ta2 : ta3;
        float gate = 1.0f / (1.0f + __expf(-zv));
        float xn = gate * gfin + (1.0f - gate) * tfin;
        xh_out[oi] = __float2half(xn);
        acc[oi] += xn;
    }
}

// ---------------- host launcher ----------------

extern "C" void kernel_launch(void* const* d_in, const int* in_sizes, int n_in,
                              void* d_out, int out_size, void* d_ws, size_t ws_size,
                              hipStream_t stream) {
    const float* user_emb = (const float*)d_in[0];
    const float* item_emb = (const float*)d_in[1];
    const float* intents  = (const float*)d_in[2];
    const float* W2       = (const float*)d_in[3];
    const float* b2       = (const float*)d_in[4];
    const float* uu_w     = (const float*)d_in[5];
    const float* ii_w     = (const float*)d_in[6];
    const int*   ui_u     = (const int*)d_in[7];
    const int*   ui_i     = (const int*)d_in[8];
    const int*   uu_h     = (const int*)d_in[9];
    const int*   uu_t     = (const int*)d_in[10];
    const int*   ii_h     = (const int*)d_in[11];
    const int*   ii_t     = (const int*)d_in[12];
    float* acc = (float*)d_out;

    char* pw = (char*)d_ws;
    auto allocb = [&](size_t nbytes) -> char* {
        char* r = pw;
        pw += (nbytes + 255) & ~(size_t)255;
        return r;
    };
    // ~219 MB total
    __half* gs   = (__half*)allocb((size_t)NN * DD * 2);
    __half* ts   = (__half*)allocb((size_t)NN * DD * 2);
    float* zp    = (float*)allocb((size_t)NN * DD * 4);
    __half* xh0  = (__half*)allocb((size_t)NN * DD * 2);
    __half* xh1  = (__half*)allocb((size_t)NN * DD * 2);
    __half* c    = (__half*)allocb((size_t)EUI * KK * 2);  // 64 MB; build scratch aliases here
    float* dinv  = (float*)allocb((size_t)NN * 4);
    float* iuu   = (float*)allocb((size_t)NU * 4);
    float* iii   = (float*)allocb((size_t)NI * 4);
    float* Wd_g  = (float*)allocb((size_t)DD * DD * 4);
    float* Wd_t  = (float*)allocb((size_t)DD * DD * 4);
    int* rp_u    = (int*)allocb(((size_t)NU + 1) * 4);
    int* rp_i    = (int*)allocb(((size_t)NI + 1) * 4);
    int* rp_uu   = (int*)allocb(((size_t)NU + 1) * 4);
    int* rp_ii   = (int*)allocb(((size_t)NI + 1) * 4);
    int* rp_ui   = (int*)allocb(((size_t)NN + 1) * 4);
    int* rp_s    = (int*)allocb(((size_t)NN + 1) * 4);
    int* headU   = (int*)allocb((size_t)EUI * 4);
    int* colUI   = (int*)allocb((size_t)2 * EUI * 4);
    int* head_s  = (int*)allocb((size_t)(EUU + EII) * 4);
    int* col_s   = (int*)allocb((size_t)(EUU + EII) * 4);
    float* bw_s  = (float*)allocb((size_t)(EUU + EII) * 4);
    int* mUI     = (int*)allocb((size_t)EUI * 4);
    float* gwUI  = (float*)allocb((size_t)2 * EUI * 4);

    char* ca = (char*)c;
    int* cur    = (int*)ca;  ca += ((size_t)NU * 4 + 255) & ~(size_t)255;
    int* lst_u  = (int*)ca;  ca += ((size_t)EUI * 4 + 255) & ~(size_t)255;
    int* lst_i  = (int*)ca;  ca += ((size_t)EUI * 4 + 255) & ~(size_t)255;
    int* lst_uu = (int*)ca;  ca += ((size_t)EUU * 4 + 255) & ~(size_t)255;
    int* lst_ii = (int*)ca;  ca += ((size_t)EII * 4 + 255) & ~(size_t)255;
    int* posU   = (int*)ca;

    const int B = 256;

    auto build_csr = [&](const int* h, int E, int n, int* rp, int* lst) {
        hipMemsetAsync(cur, 0, (size_t)n * 4, stream);
        k_count<<<cdiv(E, B), B, 0, stream>>>(h, cur, E);
        k_scan<<<1, 1024, 0, stream>>>(cur, rp, n);
        hipMemsetAsync(cur, 0, (size_t)n * 4, stream);
        k_scatter<<<cdiv(E, B), B, 0, stream>>>(h, rp, cur, lst, E);
    };

    build_csr(ui_u, EUI, NU, rp_u, lst_u);
    build_csr(ui_i, EUI, NI, rp_i, lst_i);
    build_csr(uu_h, EUU, NU, rp_uu, lst_uu);
    build_csr(ii_h, EII, NI, rp_ii, lst_ii);
    k_dinv<<<cdiv(NN, B), B, 0, stream>>>(rp_u, rp_i, dinv);
    k_rowsum_inv<<<cdiv(NU, B), B, 0, stream>>>(rp_uu, lst_uu, uu_w, iuu, NU);
    k_rowsum_inv<<<cdiv(NI, B), B, 0, stream>>>(rp_ii, lst_ii, ii_w, iii, NI);
    k_build_rp2<<<cdiv(NN + 1, B), B, 0, stream>>>(rp_u, rp_i, rp_uu, rp_ii, rp_ui, rp_s);
    k_build_ui<<<cdiv(EUI, B), B, 0, stream>>>(lst_u, ui_u, ui_i, headU, colUI, EUI);
    k_build_colI<<<cdiv(EUI, B), B, 0, stream>>>(lst_i, ui_u, colUI, EUI);
    k_posU<<<cdiv(EUI, B), B, 0, stream>>>(lst_u, posU, EUI);
    k_mapUI<<<cdiv(EUI, B), B, 0, stream>>>(lst_i, posU, mUI, EUI);
    k_build_s<<<cdiv(EUU, B), B, 0, stream>>>(lst_uu, uu_h, uu_t, uu_w, iuu, 0, 0,
                                              head_s, col_s, bw_s, EUU);
    k_build_s<<<cdiv(EII, B), B, 0, stream>>>(lst_ii, ii_h, ii_t, ii_w, iii, NU, EUU,
                                              head_s, col_s, bw_s, EII);
    k_build_gw<<<cdiv(NN, B), B, 0, stream>>>(rp_ui, colUI, dinv, gwUI, NN);
    k_wdiff<<<cdiv(DD * DD, B), B, 0, stream>>>(W2, Wd_g, Wd_t);
    k_init<<<cdiv((long)NN * DD, B), B, 0, stream>>>(user_emb, item_emb, xh0, acc);

    for (int layer = 0; layer < 2; ++layer) {
        const __half* xin = (layer == 0) ? xh0 : xh1;
        __half* xout = (layer == 0) ? xh1 : xh0;

        // ---- UI phase (2 dispatches) ----
        k_passA<<<1024, B, 0, stream>>>(headU, colUI, xin, intents, c, EUI);
        k_fused_ui<<<cdiv(NN, ROWS_PB), 512, 0, stream>>>(rp_ui, colUI, gwUI, c, mUI,
                                                          Wd_g, Wd_t, b2, xin, gs, ts, zp, NN);

        // ---- UU+II phase (2 dispatches) ----
        k_passA<<<1024, B, 0, stream>>>(head_s, col_s, xin, intents, c, EUU + EII);
        k_fused_fin<<<cdiv(NN, ROWS_PB), 512, 0, stream>>>(rp_s, col_s, bw_s, c,
                                                           W2 + DD * DD, W2 + 3 * DD * DD,
                                                           xin, gs, ts, zp, xout, acc, NN);
    }
}